// Round 7
// baseline (872.795 us; speedup 1.0000x reference)
//
#include <hip/hip_runtime.h>
#include <hip/hip_bf16.h>
#include <cstddef>

#define N_NODES 30000
#define N_EDGES 100000
#define N_TYPES 6
#define D_IN 128
#define HC 256
#define NH 8
#define CH 32

typedef __attribute__((ext_vector_type(8))) unsigned short ushort8_t;
typedef __attribute__((ext_vector_type(4))) unsigned short ushort4_t;
typedef __attribute__((ext_vector_type(8))) __bf16 bf16x8;
typedef __attribute__((ext_vector_type(4))) float floatx4;

#define FG_GRID (N_NODES / 4)   // 7500 blocks per type, 1 node per wave

__device__ inline unsigned short f2bf(float f) {
    unsigned u = __float_as_uint(f);
    u += 0x7fffu + ((u >> 16) & 1u);
    return (unsigned short)(u >> 16);
}
__device__ inline float bf2f(unsigned short u) {
    return __uint_as_float(((unsigned)u) << 16);
}

// ---------------- fills / converts ----------------
__global__ void zero4(float4* __restrict__ p, int n4) {
    int g = blockIdx.x * blockDim.x + threadIdx.x;
    if (g < n4) p[g] = make_float4(0.f, 0.f, 0.f, 0.f);
}
__global__ void zero_i(int* __restrict__ p, int n) {
    int g = blockIdx.x * blockDim.x + threadIdx.x;
    if (g < n) p[g] = 0;
}
__global__ void to_bf16(const float* __restrict__ x, unsigned short* __restrict__ o, int n4) {
    int g = blockIdx.x * blockDim.x + threadIdx.x;
    if (g >= n4) return;
    float4 v = ((const float4*)x)[g];
    ushort4_t p;
    p[0] = f2bf(v.x); p[1] = f2bf(v.y); p[2] = f2bf(v.z); p[3] = f2bf(v.w);
    *(ushort4_t*)&o[(size_t)g * 4] = p;
}

// ---------------- batched CSR build (all 6 types) ----------------
__global__ void hist_all(const int* __restrict__ ei, int* __restrict__ counts) {
    int t = blockIdx.y;
    int e = blockIdx.x * 256 + threadIdx.x;
    if (e < N_EDGES)
        atomicAdd(&counts[t * N_NODES + ei[(size_t)t * 2 * N_EDGES + N_EDGES + e]], 1);
}

#define SCAN_T 1024
#define SCAN_C 30
__global__ __launch_bounds__(1024) void scan_all(const int* __restrict__ counts_g,
                                                 int* __restrict__ row_ptr_g,
                                                 int* __restrict__ cursor_g) {
    int t = blockIdx.x;
    const int* counts = counts_g + t * N_NODES;
    int* row_ptr = row_ptr_g + t * (N_NODES + 1);
    int* cursor = cursor_g + t * N_NODES;
    __shared__ int part[SCAN_T];
    int tid = threadIdx.x;
    int base = tid * SCAN_C;
    int loc[SCAN_C];
    int s = 0;
    #pragma unroll
    for (int i = 0; i < SCAN_C; ++i) {
        int idx = base + i;
        int v = (idx < N_NODES) ? counts[idx] : 0;
        loc[i] = s; s += v;
    }
    part[tid] = s;
    __syncthreads();
    int tot = s;
    for (int d = 1; d < SCAN_T; d <<= 1) {
        int v = (tid >= d) ? part[tid - d] : 0;
        __syncthreads();
        part[tid] += v;
        __syncthreads();
    }
    int off = part[tid] - tot;
    #pragma unroll
    for (int i = 0; i < SCAN_C; ++i) {
        int idx = base + i;
        if (idx < N_NODES) { int r = off + loc[i]; row_ptr[idx] = r; cursor[idx] = r; }
    }
    if (tid == SCAN_T - 1) row_ptr[N_NODES] = part[SCAN_T - 1];
}

__global__ void fill_all(const int* __restrict__ ei, int* __restrict__ cursor,
                         int* __restrict__ elist, int* __restrict__ eorig) {
    int t = blockIdx.y;
    int e = blockIdx.x * 256 + threadIdx.x;
    if (e < N_EDGES) {
        const int* src = ei + (size_t)t * 2 * N_EDGES;
        const int* dst = src + N_EDGES;
        int pos = atomicAdd(&cursor[t * N_NODES + dst[e]], 1);
        elist[t * N_EDGES + pos] = src[e];
        eorig[t * N_EDGES + pos] = e;
    }
}

// ---------------- attention dst-weight precompute (TRANSPOSED: [h][k]) ----------------
__global__ void att_weight_all(const float* __restrict__ W1d, const float* __restrict__ a1d,
                               const float* __restrict__ W2d, const float* __restrict__ a2d,
                               float* __restrict__ wd1, float* __restrict__ wd2) {
    int g = blockIdx.x * blockDim.x + threadIdx.x;
    const int per_t = (D_IN + HC) * NH;
    if (g >= N_TYPES * per_t) return;
    int t = g / per_t, r = g % per_t;
    if (r < D_IN * NH) {
        int k = r >> 3, h = r & 7;
        const float* wr = W1d + (size_t)t * D_IN * HC + (size_t)k * HC + h * CH;
        const float* ar = a1d + t * HC + h * CH;
        float s = 0.f;
        #pragma unroll
        for (int c = 0; c < CH; ++c) s += wr[c] * ar[c];
        wd1[t * D_IN * NH + h * D_IN + k] = s;          // transposed
    } else {
        r -= D_IN * NH;
        int k = r >> 3, h = r & 7;
        const float* wr = W2d + (size_t)t * HC * HC + (size_t)k * HC + h * CH;
        const float* ar = a2d + t * HC + h * CH;
        float s = 0.f;
        #pragma unroll
        for (int c = 0; c < CH; ++c) s += wr[c] * ar[c];
        wd2[t * HC * NH + h * HC + k] = s;              // transposed
    }
}

// ---------------- weight pre-transpose+convert: Wt[j][n][k] bf16 ----------------
__global__ __launch_bounds__(256) void wt_prep(const float* __restrict__ W1s,
                                               const float* __restrict__ W2s,
                                               unsigned short* __restrict__ Wt) {
    const int j = blockIdx.z;
    const float* W = (j < 6) ? W1s + (size_t)j * D_IN * HC
                             : W2s + (size_t)(j - 6) * D_IN * HC;
    const int n0 = blockIdx.x * 64;
    const int k0 = blockIdx.y * 32;
    __shared__ unsigned short tile[32][71];
    const int t = threadIdx.x;
    {
        const int k = t >> 3, n = (t & 7) * 8;
        const float4 a = *(const float4*)&W[(size_t)(k0 + k) * HC + n0 + n];
        const float4 b = *(const float4*)&W[(size_t)(k0 + k) * HC + n0 + n + 4];
        tile[k][n + 0] = f2bf(a.x); tile[k][n + 1] = f2bf(a.y);
        tile[k][n + 2] = f2bf(a.z); tile[k][n + 3] = f2bf(a.w);
        tile[k][n + 4] = f2bf(b.x); tile[k][n + 5] = f2bf(b.y);
        tile[k][n + 6] = f2bf(b.z); tile[k][n + 7] = f2bf(b.w);
    }
    __syncthreads();
    {
        const int n = t >> 2, k = (t & 3) * 8;
        ushort8_t v;
        #pragma unroll
        for (int q = 0; q < 8; ++q) v[q] = tile[k + q][n];
        *(ushort8_t*)&Wt[((size_t)j * HC + n0 + n) * D_IN + k0 + k] = v;
    }
}

// ---------------- layer-1 dst attention logits ----------------
__global__ __launch_bounds__(256) void ed1_all(const float* __restrict__ x_tgt,
                                               const float* __restrict__ wd1,
                                               float* __restrict__ ed1g) {
    const int t = blockIdx.y;
    const int lane = threadIdx.x & 63;
    const int wv = threadIdx.x >> 6;
    const int n8 = lane >> 3, h = lane & 7;
    const int node = blockIdx.x * 32 + wv * 8 + n8;
    if (node >= N_NODES) return;
    const float* xr = x_tgt + ((size_t)t * N_NODES + node) * D_IN;
    const float* wp = wd1 + t * D_IN * NH + h * D_IN;
    float acc = 0.f;
    #pragma unroll
    for (int k = 0; k < D_IN; k += 4) {
        const float4 x4 = *(const float4*)&xr[k];
        const float4 w4 = *(const float4*)&wp[k];
        acc += x4.x * w4.x + x4.y * w4.y + x4.z * w4.z + x4.w * w4.w;
    }
    ed1g[((size_t)t * N_NODES + node) * NH + h] = acc;
}

// ---------------- ONE batched MFMA GEMM over 12 jobs ----------------
__global__ __launch_bounds__(256) void gemm_all(const unsigned short* __restrict__ A,
                                                const unsigned short* __restrict__ Wt,
                                                const float* __restrict__ att1,
                                                const float* __restrict__ att2,
                                                unsigned short* __restrict__ hs_all,
                                                float* __restrict__ es_all) {
    const int j = blockIdx.z;
    const unsigned short* B = Wt + (size_t)j * HC * D_IN;   // [n][k] bf16
    const float* att = (j < 6) ? att1 + j * HC : att2 + (j - 6) * HC;
    unsigned short* Cp = hs_all + (size_t)j * N_NODES * HC;
    float* e_out = es_all + (size_t)j * N_NODES * NH;

    __shared__ __align__(16) unsigned short As[64 * 136];
    __shared__ __align__(16) unsigned short Bs[128 * 136];

    const int tid = threadIdx.x;
    const int w = tid >> 6;
    const int lane = tid & 63;
    const int col = lane & 15;
    const int quad = lane >> 4;
    const int m0 = blockIdx.x * 64;
    const int n0 = blockIdx.y * 128;

    // stage A 64x128 (4 x 16B per thread)
    {
        const int r = tid >> 2;
        const int kc = (tid & 3) * 8;
        const int gm = m0 + r;
        #pragma unroll
        for (int c = 0; c < 4; ++c) {
            ushort8_t v = (ushort8_t){0, 0, 0, 0, 0, 0, 0, 0};
            if (gm < N_NODES) v = *(const ushort8_t*)&A[(size_t)gm * D_IN + kc + c * 32];
            *(ushort8_t*)&As[r * 136 + kc + c * 32] = v;
        }
    }
    // stage B 128x128 (8 x 16B per thread)
    {
        const int r = tid >> 1;
        const int ks = (tid & 1) * 64;
        const unsigned short* br = &B[(size_t)(n0 + r) * D_IN + ks];
        #pragma unroll
        for (int q = 0; q < 8; ++q) {
            ushort8_t v = *(const ushort8_t*)&br[q * 8];
            *(ushort8_t*)&Bs[r * 136 + ks + q * 8] = v;
        }
    }
    __syncthreads();

    floatx4 acc[8];
    #pragma unroll
    for (int ct = 0; ct < 8; ++ct) acc[ct] = (floatx4){0.f, 0.f, 0.f, 0.f};

    #pragma unroll
    for (int ks = 0; ks < 4; ++ks) {
        ushort8_t araw = *(const ushort8_t*)&As[(w * 16 + col) * 136 + ks * 32 + quad * 8];
        bf16x8 af = __builtin_bit_cast(bf16x8, araw);
        #pragma unroll
        for (int ct = 0; ct < 8; ++ct) {
            ushort8_t braw = *(const ushort8_t*)&Bs[(ct * 16 + col) * 136 + ks * 32 + quad * 8];
            bf16x8 bf = __builtin_bit_cast(bf16x8, braw);
            acc[ct] = __builtin_amdgcn_mfma_f32_16x16x32_bf16(af, bf, acc[ct], 0, 0, 0);
        }
    }

    // es epilogue (register-only + shfl; independent of LDS)
    float attv[8];
    #pragma unroll
    for (int ct = 0; ct < 8; ++ct) attv[ct] = att[n0 + ct * 16 + col];
    const int hbase = n0 >> 5;
    #pragma unroll
    for (int r = 0; r < 4; ++r) {
        float h0v = acc[0][r] * attv[0] + acc[1][r] * attv[1];
        float h1v = acc[2][r] * attv[2] + acc[3][r] * attv[3];
        float h2v = acc[4][r] * attv[4] + acc[5][r] * attv[5];
        float h3v = acc[6][r] * attv[6] + acc[7][r] * attv[7];
        #pragma unroll
        for (int off = 1; off < 16; off <<= 1) {
            h0v += __shfl_xor(h0v, off);
            h1v += __shfl_xor(h1v, off);
            h2v += __shfl_xor(h2v, off);
            h3v += __shfl_xor(h3v, off);
        }
        if (col == 0) {
            int gm = m0 + w * 16 + quad * 4 + r;
            if (gm < N_NODES)
                *(float4*)&e_out[gm * NH + hbase] = make_float4(h0v, h1v, h2v, h3v);
        }
    }

    // C writeback via LDS (reuse Bs; stride 144 ushorts -> conflict-free writes)
    __syncthreads();            // all Bs reads complete
    unsigned short* Cs = (unsigned short*)Bs;
    #pragma unroll
    for (int ct = 0; ct < 8; ++ct) {
        const int cc = ct * 16 + col;
        #pragma unroll
        for (int r = 0; r < 4; ++r)
            Cs[(w * 16 + quad * 4 + r) * 144 + cc] = f2bf(acc[ct][r]);
    }
    __syncthreads();
    {
        const int r = tid >> 2;
        const int c0 = (tid & 3) * 32;
        const int gm = m0 + r;
        if (gm < N_NODES) {
            #pragma unroll
            for (int q = 0; q < 4; ++q) {
                ushort8_t v = *(const ushort8_t*)&Cs[r * 144 + c0 + q * 8];
                *(ushort8_t*)&Cp[(size_t)gm * HC + n0 + c0 + q * 8] = v;
            }
        }
    }
}

// ---------------- pipelined edge-chunk helpers ----------------
__device__ inline void edge4(const float* __restrict__ es,
                             const unsigned short* __restrict__ hs,
                             int s_pre, int i, int cm,
                             int h_l, int lane, float ed_mine,
                             float& den, float4& acc) {
    const int i1 = (i + 1 < cm) ? i + 1 : cm;
    const int i2 = (i + 2 < cm) ? i + 2 : cm;
    const int i3 = (i + 3 < cm) ? i + 3 : cm;
    const int s0 = __shfl(s_pre, i);
    const int s1 = __shfl(s_pre, i1);
    const int s2 = __shfl(s_pre, i2);
    const int s3 = __shfl(s_pre, i3);
    float q0 = es[s0 * NH + h_l];
    float q1 = es[s1 * NH + h_l];
    float q2 = es[s2 * NH + h_l];
    float q3 = es[s3 * NH + h_l];
    const ushort4_t v0 = *(const ushort4_t*)&hs[(size_t)s0 * HC + lane * 4];
    const ushort4_t v1 = *(const ushort4_t*)&hs[(size_t)s1 * HC + lane * 4];
    const ushort4_t v2 = *(const ushort4_t*)&hs[(size_t)s2 * HC + lane * 4];
    const ushort4_t v3 = *(const ushort4_t*)&hs[(size_t)s3 * HC + lane * 4];
    q0 += ed_mine; q0 = (q0 >= 0.f) ? q0 : 0.2f * q0;
    q1 += ed_mine; q1 = (q1 >= 0.f) ? q1 : 0.2f * q1;
    q2 += ed_mine; q2 = (q2 >= 0.f) ? q2 : 0.2f * q2;
    q3 += ed_mine; q3 = (q3 >= 0.f) ? q3 : 0.2f * q3;
    const float x0 = __expf(q0);
    const float x1 = (i + 1 <= cm) ? __expf(q1) : 0.f;
    const float x2 = (i + 2 <= cm) ? __expf(q2) : 0.f;
    const float x3 = (i + 3 <= cm) ? __expf(q3) : 0.f;
    den += (x0 + x1) + (x2 + x3);
    acc.x += x0 * bf2f(v0[0]) + x1 * bf2f(v1[0]) + x2 * bf2f(v2[0]) + x3 * bf2f(v3[0]);
    acc.y += x0 * bf2f(v0[1]) + x1 * bf2f(v1[1]) + x2 * bf2f(v2[1]) + x3 * bf2f(v3[1]);
    acc.z += x0 * bf2f(v0[2]) + x1 * bf2f(v1[2]) + x2 * bf2f(v2[2]) + x3 * bf2f(v3[2]);
    acc.w += x0 * bf2f(v0[3]) + x1 * bf2f(v1[3]) + x2 * bf2f(v2[3]) + x3 * bf2f(v3[3]);
}

__device__ inline void edge1(const float* __restrict__ es,
                             const unsigned short* __restrict__ hs,
                             int s, int h_l, int lane, float ed_mine,
                             float& den, float4& acc) {
    float x = es[s * NH + h_l] + ed_mine;
    x = (x >= 0.f) ? x : 0.2f * x;
    const float ex = __expf(x);
    den += ex;
    const ushort4_t hv = *(const ushort4_t*)&hs[(size_t)s * HC + lane * 4];
    acc.x += ex * bf2f(hv[0]); acc.y += ex * bf2f(hv[1]);
    acc.z += ex * bf2f(hv[2]); acc.w += ex * bf2f(hv[3]);
}

// ---------------- FUSED layer1+layer2 per-node gather (+ inline alpha2 write) ----
__global__ __launch_bounds__(256) void fused_gather_all(
        const int* __restrict__ row_ptr_g, const int* __restrict__ elist_g,
        const int* __restrict__ eorig_g,
        const float* __restrict__ es_all, const float* __restrict__ ed1g,
        const unsigned short* __restrict__ hs_all,
        const float* __restrict__ b1, const float* __restrict__ b2,
        const float* __restrict__ gamma, const float* __restrict__ beta,
        const float* __restrict__ wd2,
        float* __restrict__ alpha_out,
        float* __restrict__ ppart) {
    const int t = blockIdx.y;
    const int* row_ptr = row_ptr_g + t * (N_NODES + 1);
    const int* elist = elist_g + t * N_EDGES;
    const int* eorig = eorig_g + t * N_EDGES;
    const float* es1 = es_all + (size_t)t * N_NODES * NH;
    const float* es2 = es_all + (size_t)(6 + t) * N_NODES * NH;
    const unsigned short* hs1 = hs_all + (size_t)t * N_NODES * HC;
    const unsigned short* hs2 = hs_all + (size_t)(6 + t) * N_NODES * HC;
    const float* gam = gamma + t * HC;
    const float* bet = beta + t * HC;
    const float* w2 = wd2 + t * HC * NH;
    float* aout = alpha_out + (size_t)t * N_EDGES * NH;

    const int lane = threadIdx.x & 63;
    const int w = threadIdx.x >> 6;
    const int d = blockIdx.x * 4 + w;
    const int h_l = lane >> 3;

    const float ed_mine = ed1g[((size_t)t * N_NODES + d) * NH + h_l];
    const int e0 = row_ptr[d], e1n = row_ptr[d + 1];
    const int cnt = e1n - e0;
    int s_pre = 0, eo_pre = 0;
    if (lane < cnt) {
        s_pre = elist[e0 + lane];
        eo_pre = eorig[e0 + lane];
    }

    float den1 = 0.f, den2 = 0.f;
    float4 acc1 = make_float4(0.f, 0.f, 0.f, 0.f);
    float4 acc2 = make_float4(0.f, 0.f, 0.f, 0.f);

    float q20, q21, q22, q23;
    float ax0 = 0.f, ax1 = 0.f, ax2 = 0.f, ax3 = 0.f;   // layer-2 exp values (fast path)
    ushort4_t v20, v21, v22, v23;
    const bool fast = (cnt > 0) && (cnt <= 4);

    if (fast) {
        const int cm = cnt - 1;
        const int s0 = __shfl(s_pre, 0);
        const int s1 = __shfl(s_pre, (1 < cm) ? 1 : cm);
        const int s2 = __shfl(s_pre, (2 < cm) ? 2 : cm);
        const int s3 = __shfl(s_pre, cm);
        float q10 = es1[s0 * NH + h_l];
        float q11 = es1[s1 * NH + h_l];
        float q12 = es1[s2 * NH + h_l];
        float q13 = es1[s3 * NH + h_l];
        const ushort4_t v10 = *(const ushort4_t*)&hs1[(size_t)s0 * HC + lane * 4];
        const ushort4_t v11 = *(const ushort4_t*)&hs1[(size_t)s1 * HC + lane * 4];
        const ushort4_t v12 = *(const ushort4_t*)&hs1[(size_t)s2 * HC + lane * 4];
        const ushort4_t v13 = *(const ushort4_t*)&hs1[(size_t)s3 * HC + lane * 4];
        q20 = es2[s0 * NH + h_l];
        q21 = es2[s1 * NH + h_l];
        q22 = es2[s2 * NH + h_l];
        q23 = es2[s3 * NH + h_l];
        v20 = *(const ushort4_t*)&hs2[(size_t)s0 * HC + lane * 4];
        v21 = *(const ushort4_t*)&hs2[(size_t)s1 * HC + lane * 4];
        v22 = *(const ushort4_t*)&hs2[(size_t)s2 * HC + lane * 4];
        v23 = *(const ushort4_t*)&hs2[(size_t)s3 * HC + lane * 4];
        q10 += ed_mine; q10 = (q10 >= 0.f) ? q10 : 0.2f * q10;
        q11 += ed_mine; q11 = (q11 >= 0.f) ? q11 : 0.2f * q11;
        q12 += ed_mine; q12 = (q12 >= 0.f) ? q12 : 0.2f * q12;
        q13 += ed_mine; q13 = (q13 >= 0.f) ? q13 : 0.2f * q13;
        const float x0 = __expf(q10);
        const float x1 = (cnt > 1) ? __expf(q11) : 0.f;
        const float x2 = (cnt > 2) ? __expf(q12) : 0.f;
        const float x3 = (cnt > 3) ? __expf(q13) : 0.f;
        den1 = (x0 + x1) + (x2 + x3);
        acc1.x = x0 * bf2f(v10[0]) + x1 * bf2f(v11[0]) + x2 * bf2f(v12[0]) + x3 * bf2f(v13[0]);
        acc1.y = x0 * bf2f(v10[1]) + x1 * bf2f(v11[1]) + x2 * bf2f(v12[1]) + x3 * bf2f(v13[1]);
        acc1.z = x0 * bf2f(v10[2]) + x1 * bf2f(v11[2]) + x2 * bf2f(v12[2]) + x3 * bf2f(v13[2]);
        acc1.w = x0 * bf2f(v10[3]) + x1 * bf2f(v11[3]) + x2 * bf2f(v12[3]) + x3 * bf2f(v13[3]);
    } else if (cnt > 0) {
        const int c1 = (cnt < 64) ? cnt : 64;
        const int cm = c1 - 1;
        for (int i = 0; i < c1; i += 4)
            edge4(es1, hs1, s_pre, i, cm, h_l, lane, ed_mine, den1, acc1);
        if (cnt > 64)
            for (int ii = e0 + 64; ii < e1n; ++ii)
                edge1(es1, hs1, elist[ii], h_l, lane, ed_mine, den1, acc1);
    }

    const float inv1 = 1.f / (den1 + 1e-16f);
    const float4 bv1 = *(const float4*)&b1[t * HC + lane * 4];
    acc1.x = acc1.x * inv1 + bv1.x; acc1.y = acc1.y * inv1 + bv1.y;
    acc1.z = acc1.z * inv1 + bv1.z; acc1.w = acc1.w * inv1 + bv1.w;

    float s1 = acc1.x + acc1.y + acc1.z + acc1.w;
    float s2 = acc1.x * acc1.x + acc1.y * acc1.y + acc1.z * acc1.z + acc1.w * acc1.w;
    #pragma unroll
    for (int off = 1; off < 64; off <<= 1) { s1 += __shfl_xor(s1, off); s2 += __shfl_xor(s2, off); }
    const float mu = s1 * (1.f / 256.f);
    const float var = s2 * (1.f / 256.f) - mu * mu;
    const float rstd = rsqrtf(var + 1e-5f);
    const float4 g4 = *(const float4*)&gam[lane * 4];
    const float4 b4 = *(const float4*)&bet[lane * 4];
    const float ya0 = fmaxf((acc1.x - mu) * rstd * g4.x + b4.x, 0.f);
    const float ya1 = fmaxf((acc1.y - mu) * rstd * g4.y + b4.y, 0.f);
    const float ya2 = fmaxf((acc1.z - mu) * rstd * g4.z + b4.z, 0.f);
    const float ya3 = fmaxf((acc1.w - mu) * rstd * g4.w + b4.w, 0.f);

    __shared__ __align__(16) float ya_s[4][256];
    {
        const int c0 = lane * 4;
        const int widx = (c0 & ~31) | ((c0 & 31) ^ ((lane >> 3) << 2));
        *(float4*)&ya_s[w][widx] = make_float4(ya0, ya1, ya2, ya3);
    }
    const int k8 = lane >> 3;
    const int hh = lane & 7;
    const float* w2h = w2 + hh * HC;
    float e2 = 0.f;
    #pragma unroll
    for (int jj = 0; jj < 8; ++jj) {
        const int idx = k8 * 32 + ((jj * 4) ^ (k8 << 2));
        const float4 y = *(const float4*)&ya_s[w][idx];
        const float4 wv = *(const float4*)&w2h[k8 * 32 + jj * 4];
        e2 += y.x * wv.x + y.y * wv.y + y.z * wv.z + y.w * wv.w;
    }
    e2 += __shfl_xor(e2, 8);
    e2 += __shfl_xor(e2, 16);
    e2 += __shfl_xor(e2, 32);
    const float ed2_mine = __shfl(e2, h_l);

    if (fast) {
        q20 += ed2_mine; q20 = (q20 >= 0.f) ? q20 : 0.2f * q20;
        q21 += ed2_mine; q21 = (q21 >= 0.f) ? q21 : 0.2f * q21;
        q22 += ed2_mine; q22 = (q22 >= 0.f) ? q22 : 0.2f * q22;
        q23 += ed2_mine; q23 = (q23 >= 0.f) ? q23 : 0.2f * q23;
        ax0 = __expf(q20);
        ax1 = (cnt > 1) ? __expf(q21) : 0.f;
        ax2 = (cnt > 2) ? __expf(q22) : 0.f;
        ax3 = (cnt > 3) ? __expf(q23) : 0.f;
        den2 = (ax0 + ax1) + (ax2 + ax3);
        acc2.x = ax0 * bf2f(v20[0]) + ax1 * bf2f(v21[0]) + ax2 * bf2f(v22[0]) + ax3 * bf2f(v23[0]);
        acc2.y = ax0 * bf2f(v20[1]) + ax1 * bf2f(v21[1]) + ax2 * bf2f(v22[1]) + ax3 * bf2f(v23[1]);
        acc2.z = ax0 * bf2f(v20[2]) + ax1 * bf2f(v21[2]) + ax2 * bf2f(v22[2]) + ax3 * bf2f(v23[2]);
        acc2.w = ax0 * bf2f(v20[3]) + ax1 * bf2f(v21[3]) + ax2 * bf2f(v22[3]) + ax3 * bf2f(v23[3]);
    } else if (cnt > 0) {
        const int c1 = (cnt < 64) ? cnt : 64;
        const int cm = c1 - 1;
        for (int i = 0; i < c1; i += 4)
            edge4(es2, hs2, s_pre, i, cm, h_l, lane, ed2_mine, den2, acc2);
        if (cnt > 64)
            for (int ii = e0 + 64; ii < e1n; ++ii)
                edge1(es2, hs2, elist[ii], h_l, lane, ed2_mine, den2, acc2);
    }

    const float inv2 = 1.f / (den2 + 1e-16f);

    // ---- inline alpha2 writes (replaces the alpha_all kernel) ----
    // NOTE: all __shfl broadcasts are in FULL-WAVE control flow (reading a
    // lane that is inactive in the current EXEC mask is undefined on CDNA);
    // only the stores themselves are lane-guarded.
    if (fast) {
        const int eo0 = __shfl(eo_pre, 0);
        const int eo1 = __shfl(eo_pre, 1);
        const int eo2 = __shfl(eo_pre, 2);
        const int eo3 = __shfl(eo_pre, 3);
        if ((lane & 7) == 0) {
            aout[(size_t)eo0 * NH + h_l] = ax0 * inv2;
            if (cnt > 1) aout[(size_t)eo1 * NH + h_l] = ax1 * inv2;
            if (cnt > 2) aout[(size_t)eo2 * NH + h_l] = ax2 * inv2;
            if (cnt > 3) aout[(size_t)eo3 * NH + h_l] = ax3 * inv2;
        }
    } else if (cnt > 0) {
        const int c1 = (cnt < 64) ? cnt : 64;
        for (int i = 0; i < c1; ++i) {
            const int si = __shfl(s_pre, i);
            const int eo = __shfl(eo_pre, i);
            if ((lane & 7) == 0) {
                float x = es2[si * NH + h_l] + ed2_mine;
                x = (x >= 0.f) ? x : 0.2f * x;
                aout[(size_t)eo * NH + h_l] = __expf(x) * inv2;
            }
        }
        if (cnt > 64)
            for (int ii = e0 + 64; ii < e1n; ++ii) {
                const int si = elist[ii];
                const int eo = eorig[ii];
                if ((lane & 7) == 0) {
                    float x = es2[si * NH + h_l] + ed2_mine;
                    x = (x >= 0.f) ? x : 0.2f * x;
                    aout[(size_t)eo * NH + h_l] = __expf(x) * inv2;
                }
            }
    }

    const float4 bv2 = *(const float4*)&b2[t * HC + lane * 4];
    acc2.x = acc2.x * inv2 + bv2.x; acc2.y = acc2.y * inv2 + bv2.y;
    acc2.z = acc2.z * inv2 + bv2.z; acc2.w = acc2.w * inv2 + bv2.w;

    float t1 = acc2.x + acc2.y + acc2.z + acc2.w;
    float t2 = acc2.x * acc2.x + acc2.y * acc2.y + acc2.z * acc2.z + acc2.w * acc2.w;
    #pragma unroll
    for (int off = 1; off < 64; off <<= 1) { t1 += __shfl_xor(t1, off); t2 += __shfl_xor(t2, off); }
    const float mu2 = t1 * (1.f / 256.f);
    const float var2 = t2 * (1.f / 256.f) - mu2 * mu2;
    const float rstd2 = rsqrtf(var2 + 1e-5f);
    float4 pool;
    pool.x = fmaxf((acc2.x - mu2) * rstd2 * g4.x + b4.x, 0.f);
    pool.y = fmaxf((acc2.y - mu2) * rstd2 * g4.y + b4.y, 0.f);
    pool.z = fmaxf((acc2.z - mu2) * rstd2 * g4.z + b4.z, 0.f);
    pool.w = fmaxf((acc2.w - mu2) * rstd2 * g4.w + b4.w, 0.f);

    // ---- block pool partial ----
    __shared__ __align__(16) float sacc[4][260];
    *(float4*)&sacc[w][lane * 4] = pool;
    __syncthreads();
    const int tid = threadIdx.x;
    float tot = sacc[0][tid] + sacc[1][tid] + sacc[2][tid] + sacc[3][tid];
    ppart[((size_t)t * FG_GRID + blockIdx.x) * HC + tid] = tot;
}

// ---------------- batched pooled-partial reduce ----------------
__global__ __launch_bounds__(256) void pool_reduce_all(const float* __restrict__ ppart,
                                                       float* __restrict__ psums) {
    int t = blockIdx.y;
    const float* part = ppart + (size_t)t * FG_GRID * HC;
    int tid = threadIdx.x;
    float acc = 0.f;
    for (int b = blockIdx.x; b < FG_GRID; b += gridDim.x)
        acc += part[(size_t)b * HC + tid];
    atomicAdd(&psums[t * HC + tid], acc);
}

// ---------------- x_pkg column sums ----------------
__global__ __launch_bounds__(256) void pkg_accum(const float* __restrict__ x, float* __restrict__ sums) {
    int tid = threadIdx.x;
    int col = tid & 127;
    int rof = tid >> 7;
    float acc = 0.f;
    for (int r = blockIdx.x * 2 + rof; r < N_NODES; r += gridDim.x * 2)
        acc += x[(size_t)r * D_IN + col];
    atomicAdd(&sums[col], acc);
}

// ---------------- final classifier dot ----------------
__global__ __launch_bounds__(256) void logits_k(const float* __restrict__ psums,
                                                const float* __restrict__ ksums,
                                                const float* __restrict__ Wc,
                                                const float* __restrict__ bc,
                                                float* __restrict__ out) {
    int tid = threadIdx.x;
    const float inv = 1.f / (float)N_NODES;
    float acc = 0.f;
    for (int i = tid; i < N_TYPES * HC; i += 256) acc += psums[i] * inv * Wc[i];
    if (tid < D_IN) acc += ksums[tid] * inv * Wc[N_TYPES * HC + tid];
    #pragma unroll
    for (int off = 32; off; off >>= 1) acc += __shfl_down(acc, off);
    __shared__ float w[4];
    if ((tid & 63) == 0) w[tid >> 6] = acc;
    __syncthreads();
    if (tid == 0) out[0] = w[0] + w[1] + w[2] + w[3] + bc[0];
}

static inline void zf(float* p, int n, hipStream_t stream) {
    int n4 = (n + 3) >> 2;
    zero4<<<(n4 + 255) / 256, 256, 0, stream>>>((float4*)p, n4);
}

extern "C" void kernel_launch(void* const* d_in, const int* in_sizes, int n_in,
                              void* d_out, int out_size, void* d_ws, size_t ws_size,
                              hipStream_t stream) {
    const float* x_pkg    = (const float*)d_in[0];
    const float* x_tgt    = (const float*)d_in[1];
    const int*   ei       = (const int*)d_in[2];
    const float* W1_src   = (const float*)d_in[3];
    const float* W1_dst   = (const float*)d_in[4];
    const float* att1_src = (const float*)d_in[5];
    const float* att1_dst = (const float*)d_in[6];
    const float* b1       = (const float*)d_in[7];
    const float* W2_src   = (const float*)d_in[8];
    const float* W2_dst   = (const float*)d_in[9];
    const float* att2_src = (const float*)d_in[10];
    const float* att2_dst = (const float*)d_in[11];
    const float* b2       = (const float*)d_in[12];
    const float* gamma    = (const float*)d_in[13];
    const float* beta     = (const float*)d_in[14];
    const float* Wc       = (const float*)d_in[15];
    const float* bc       = (const float*)d_in[16];
    float* out = (float*)d_out;

    // ---- workspace layout ----
    char* wsb = (char*)d_ws;
    unsigned short* xpkg_bf = (unsigned short*)wsb;                    // 30000*128
    unsigned short* hs_all  = xpkg_bf + (size_t)N_NODES * D_IN;        // 12*30000*256
    float* es_all   = (float*)(hs_all + (size_t)12 * N_NODES * HC);    // 12*30000*8
    float* psums    = es_all + (size_t)12 * N_NODES * NH;              // 1536
    float* ksums    = psums + N_TYPES * HC;                            // 128
    float* wd1      = ksums + D_IN;                                    // 6*128*8 (transposed [h][k])
    float* wd2      = wd1 + N_TYPES * D_IN * NH;                       // 6*256*8 (transposed [h][c])
    unsigned short* Wt = (unsigned short*)(wd2 + N_TYPES * HC * NH);   // 12*256*128 bf16
    float* ed1g     = (float*)(Wt + (size_t)12 * HC * D_IN);           // 6*30000*8
    float* ppart    = ed1g + (size_t)N_TYPES * N_NODES * NH;           // 6*FG_GRID*256
    int* counts  = (int*)(ppart + (size_t)N_TYPES * FG_GRID * HC);     // 6*30000
    int* row_ptr = counts + N_TYPES * N_NODES;                         // 6*30001
    int* cursor  = row_ptr + N_TYPES * (N_NODES + 1);                  // 6*30000
    int* elist   = cursor + N_TYPES * N_NODES;                         // 6*100000
    int* eorig   = elist + N_TYPES * N_EDGES;                          // 6*100000

    dim3 egrid((N_EDGES + 255) / 256, N_TYPES);

    // ---- setup ----
    zf(psums, N_TYPES * HC + D_IN, stream);   // psums + ksums contiguous
    pkg_accum<<<256, 256, 0, stream>>>(x_pkg, ksums);
    {
        int tot = N_TYPES * (D_IN + HC) * NH;
        att_weight_all<<<(tot + 255) / 256, 256, 0, stream>>>(W1_dst, att1_dst, W2_dst, att2_dst, wd1, wd2);
    }
    {
        dim3 g(4, 4, 12);
        wt_prep<<<g, 256, 0, stream>>>(W1_src, W2_src, Wt);
    }
    {
        dim3 g((N_NODES + 31) / 32, N_TYPES);
        ed1_all<<<g, 256, 0, stream>>>(x_tgt, wd1, ed1g);
    }
    to_bf16<<<((N_NODES * D_IN / 4) + 255) / 256, 256, 0, stream>>>(x_pkg, xpkg_bf, N_NODES * D_IN / 4);
    zero_i<<<(N_TYPES * N_NODES + 255) / 256, 256, 0, stream>>>(counts, N_TYPES * N_NODES);
    hist_all<<<egrid, 256, 0, stream>>>(ei, counts);
    scan_all<<<N_TYPES, SCAN_T, 0, stream>>>(counts, row_ptr, cursor);
    fill_all<<<egrid, 256, 0, stream>>>(ei, cursor, elist, eorig);

    // ---- one fat GEMM: all 12 src-side projections (n-tile 128) ----
    {
        dim3 g((N_NODES + 63) / 64, 2, 12);
        gemm_all<<<g, 256, 0, stream>>>(xpkg_bf, Wt, att1_src, att2_src,
                                        hs_all, es_all);
    }

    // ---- FUSED layer1 + layer2 + inline alpha ----
    {
        dim3 g(FG_GRID, N_TYPES);
        fused_gather_all<<<g, 256, 0, stream>>>(row_ptr, elist, eorig, es_all, ed1g, hs_all,
                                                b1, b2, gamma, beta, wd2,
                                                out + 1, ppart);
    }
    {
        dim3 g(64, N_TYPES);
        pool_reduce_all<<<g, 256, 0, stream>>>(ppart, psums);
    }

    logits_k<<<1, 256, 0, stream>>>(psums, ksums, Wc, bc, out);
}

// Round 8
// 848.501 us; speedup vs baseline: 1.0286x; 1.0286x over previous
//
#include <hip/hip_runtime.h>
#include <hip/hip_bf16.h>
#include <cstddef>

#define N_NODES 30000
#define N_EDGES 100000
#define N_TYPES 6
#define D_IN 128
#define HC 256
#define NH 8
#define CH 32

typedef __attribute__((ext_vector_type(8))) unsigned short ushort8_t;
typedef __attribute__((ext_vector_type(4))) unsigned short ushort4_t;
typedef __attribute__((ext_vector_type(8))) __bf16 bf16x8;
typedef __attribute__((ext_vector_type(4))) float floatx4;

#define FG_GRID (N_NODES / 4)   // 7500 blocks per type, 1 node per wave

__device__ inline unsigned short f2bf(float f) {
    unsigned u = __float_as_uint(f);
    u += 0x7fffu + ((u >> 16) & 1u);
    return (unsigned short)(u >> 16);
}
__device__ inline float bf2f(unsigned short u) {
    return __uint_as_float(((unsigned)u) << 16);
}

// ---------------- fills / converts ----------------
__global__ void zero4(float4* __restrict__ p, int n4) {
    int g = blockIdx.x * blockDim.x + threadIdx.x;
    if (g < n4) p[g] = make_float4(0.f, 0.f, 0.f, 0.f);
}
__global__ void zero_i(int* __restrict__ p, int n) {
    int g = blockIdx.x * blockDim.x + threadIdx.x;
    if (g < n) p[g] = 0;
}
__global__ void to_bf16(const float* __restrict__ x, unsigned short* __restrict__ o, int n4) {
    int g = blockIdx.x * blockDim.x + threadIdx.x;
    if (g >= n4) return;
    float4 v = ((const float4*)x)[g];
    ushort4_t p;
    p[0] = f2bf(v.x); p[1] = f2bf(v.y); p[2] = f2bf(v.z); p[3] = f2bf(v.w);
    *(ushort4_t*)&o[(size_t)g * 4] = p;
}

// ---------------- batched CSR build (all 6 types) ----------------
__global__ void hist_all(const int* __restrict__ ei, int* __restrict__ counts) {
    int t = blockIdx.y;
    int e = blockIdx.x * 256 + threadIdx.x;
    if (e < N_EDGES)
        atomicAdd(&counts[t * N_NODES + ei[(size_t)t * 2 * N_EDGES + N_EDGES + e]], 1);
}

#define SCAN_T 1024
#define SCAN_C 30
__global__ __launch_bounds__(1024) void scan_all(const int* __restrict__ counts_g,
                                                 int* __restrict__ row_ptr_g,
                                                 int* __restrict__ cursor_g) {
    int t = blockIdx.x;
    const int* counts = counts_g + t * N_NODES;
    int* row_ptr = row_ptr_g + t * (N_NODES + 1);
    int* cursor = cursor_g + t * N_NODES;
    __shared__ int part[SCAN_T];
    int tid = threadIdx.x;
    int base = tid * SCAN_C;
    int loc[SCAN_C];
    int s = 0;
    #pragma unroll
    for (int i = 0; i < SCAN_C; ++i) {
        int idx = base + i;
        int v = (idx < N_NODES) ? counts[idx] : 0;
        loc[i] = s; s += v;
    }
    part[tid] = s;
    __syncthreads();
    int tot = s;
    for (int d = 1; d < SCAN_T; d <<= 1) {
        int v = (tid >= d) ? part[tid - d] : 0;
        __syncthreads();
        part[tid] += v;
        __syncthreads();
    }
    int off = part[tid] - tot;
    #pragma unroll
    for (int i = 0; i < SCAN_C; ++i) {
        int idx = base + i;
        if (idx < N_NODES) { int r = off + loc[i]; row_ptr[idx] = r; cursor[idx] = r; }
    }
    if (tid == SCAN_T - 1) row_ptr[N_NODES] = part[SCAN_T - 1];
}

// fill CSR + dense first-4-edges table (src only). edense pre-zeroed so
// unwritten slots read node 0 (harmless: their exp terms are masked by cnt).
__global__ void fill_all(const int* __restrict__ ei, const int* __restrict__ row_ptr_g,
                         int* __restrict__ cursor,
                         int* __restrict__ elist, int* __restrict__ edense) {
    int t = blockIdx.y;
    int e = blockIdx.x * 256 + threadIdx.x;
    if (e < N_EDGES) {
        const int* src = ei + (size_t)t * 2 * N_EDGES;
        const int* dst = src + N_EDGES;
        const int d = dst[e];
        int pos = atomicAdd(&cursor[t * N_NODES + d], 1);
        elist[t * N_EDGES + pos] = src[e];
        int loc = pos - row_ptr_g[t * (N_NODES + 1) + d];
        if (loc < 4)
            edense[((size_t)t * N_NODES + d) * 4 + loc] = src[e];
    }
}

// ---------------- attention dst-weight precompute (TRANSPOSED: [h][k]) ----------------
__global__ void att_weight_all(const float* __restrict__ W1d, const float* __restrict__ a1d,
                               const float* __restrict__ W2d, const float* __restrict__ a2d,
                               float* __restrict__ wd1, float* __restrict__ wd2) {
    int g = blockIdx.x * blockDim.x + threadIdx.x;
    const int per_t = (D_IN + HC) * NH;
    if (g >= N_TYPES * per_t) return;
    int t = g / per_t, r = g % per_t;
    if (r < D_IN * NH) {
        int k = r >> 3, h = r & 7;
        const float* wr = W1d + (size_t)t * D_IN * HC + (size_t)k * HC + h * CH;
        const float* ar = a1d + t * HC + h * CH;
        float s = 0.f;
        #pragma unroll
        for (int c = 0; c < CH; ++c) s += wr[c] * ar[c];
        wd1[t * D_IN * NH + h * D_IN + k] = s;          // transposed
    } else {
        r -= D_IN * NH;
        int k = r >> 3, h = r & 7;
        const float* wr = W2d + (size_t)t * HC * HC + (size_t)k * HC + h * CH;
        const float* ar = a2d + t * HC + h * CH;
        float s = 0.f;
        #pragma unroll
        for (int c = 0; c < CH; ++c) s += wr[c] * ar[c];
        wd2[t * HC * NH + h * HC + k] = s;              // transposed
    }
}

// ---------------- weight pre-transpose+convert: Wt[j][n][k] bf16 ----------------
__global__ __launch_bounds__(256) void wt_prep(const float* __restrict__ W1s,
                                               const float* __restrict__ W2s,
                                               unsigned short* __restrict__ Wt) {
    const int j = blockIdx.z;
    const float* W = (j < 6) ? W1s + (size_t)j * D_IN * HC
                             : W2s + (size_t)(j - 6) * D_IN * HC;
    const int n0 = blockIdx.x * 64;
    const int k0 = blockIdx.y * 32;
    __shared__ unsigned short tile[32][71];
    const int t = threadIdx.x;
    {
        const int k = t >> 3, n = (t & 7) * 8;
        const float4 a = *(const float4*)&W[(size_t)(k0 + k) * HC + n0 + n];
        const float4 b = *(const float4*)&W[(size_t)(k0 + k) * HC + n0 + n + 4];
        tile[k][n + 0] = f2bf(a.x); tile[k][n + 1] = f2bf(a.y);
        tile[k][n + 2] = f2bf(a.z); tile[k][n + 3] = f2bf(a.w);
        tile[k][n + 4] = f2bf(b.x); tile[k][n + 5] = f2bf(b.y);
        tile[k][n + 6] = f2bf(b.z); tile[k][n + 7] = f2bf(b.w);
    }
    __syncthreads();
    {
        const int n = t >> 2, k = (t & 3) * 8;
        ushort8_t v;
        #pragma unroll
        for (int q = 0; q < 8; ++q) v[q] = tile[k + q][n];
        *(ushort8_t*)&Wt[((size_t)j * HC + n0 + n) * D_IN + k0 + k] = v;
    }
}

// ---------------- layer-1 dst attention logits ----------------
__global__ __launch_bounds__(256) void ed1_all(const float* __restrict__ x_tgt,
                                               const float* __restrict__ wd1,
                                               float* __restrict__ ed1g) {
    const int t = blockIdx.y;
    const int lane = threadIdx.x & 63;
    const int wv = threadIdx.x >> 6;
    const int n8 = lane >> 3, h = lane & 7;
    const int node = blockIdx.x * 32 + wv * 8 + n8;
    if (node >= N_NODES) return;
    const float* xr = x_tgt + ((size_t)t * N_NODES + node) * D_IN;
    const float* wp = wd1 + t * D_IN * NH + h * D_IN;
    float acc = 0.f;
    #pragma unroll
    for (int k = 0; k < D_IN; k += 4) {
        const float4 x4 = *(const float4*)&xr[k];
        const float4 w4 = *(const float4*)&wp[k];
        acc += x4.x * w4.x + x4.y * w4.y + x4.z * w4.z + x4.w * w4.w;
    }
    ed1g[((size_t)t * N_NODES + node) * NH + h] = acc;
}

// ---------------- ONE batched MFMA GEMM over 12 jobs ----------------
__global__ __launch_bounds__(256) void gemm_all(const unsigned short* __restrict__ A,
                                                const unsigned short* __restrict__ Wt,
                                                const float* __restrict__ att1,
                                                const float* __restrict__ att2,
                                                unsigned short* __restrict__ hs_all,
                                                float* __restrict__ es_all) {
    const int j = blockIdx.z;
    const unsigned short* B = Wt + (size_t)j * HC * D_IN;   // [n][k] bf16
    const float* att = (j < 6) ? att1 + j * HC : att2 + (j - 6) * HC;
    unsigned short* Cp = hs_all + (size_t)j * N_NODES * HC;
    float* e_out = es_all + (size_t)j * N_NODES * NH;

    __shared__ __align__(16) unsigned short As[64 * 136];
    __shared__ __align__(16) unsigned short Bs[128 * 136];

    const int tid = threadIdx.x;
    const int w = tid >> 6;
    const int lane = tid & 63;
    const int col = lane & 15;
    const int quad = lane >> 4;
    const int m0 = blockIdx.x * 64;
    const int n0 = blockIdx.y * 128;

    // stage A 64x128 (4 x 16B per thread)
    {
        const int r = tid >> 2;
        const int kc = (tid & 3) * 8;
        const int gm = m0 + r;
        #pragma unroll
        for (int c = 0; c < 4; ++c) {
            ushort8_t v = (ushort8_t){0, 0, 0, 0, 0, 0, 0, 0};
            if (gm < N_NODES) v = *(const ushort8_t*)&A[(size_t)gm * D_IN + kc + c * 32];
            *(ushort8_t*)&As[r * 136 + kc + c * 32] = v;
        }
    }
    // stage B 128x128 (8 x 16B per thread)
    {
        const int r = tid >> 1;
        const int ks = (tid & 1) * 64;
        const unsigned short* br = &B[(size_t)(n0 + r) * D_IN + ks];
        #pragma unroll
        for (int q = 0; q < 8; ++q) {
            ushort8_t v = *(const ushort8_t*)&br[q * 8];
            *(ushort8_t*)&Bs[r * 136 + ks + q * 8] = v;
        }
    }
    __syncthreads();

    floatx4 acc[8];
    #pragma unroll
    for (int ct = 0; ct < 8; ++ct) acc[ct] = (floatx4){0.f, 0.f, 0.f, 0.f};

    #pragma unroll
    for (int ks = 0; ks < 4; ++ks) {
        ushort8_t araw = *(const ushort8_t*)&As[(w * 16 + col) * 136 + ks * 32 + quad * 8];
        bf16x8 af = __builtin_bit_cast(bf16x8, araw);
        #pragma unroll
        for (int ct = 0; ct < 8; ++ct) {
            ushort8_t braw = *(const ushort8_t*)&Bs[(ct * 16 + col) * 136 + ks * 32 + quad * 8];
            bf16x8 bf = __builtin_bit_cast(bf16x8, braw);
            acc[ct] = __builtin_amdgcn_mfma_f32_16x16x32_bf16(af, bf, acc[ct], 0, 0, 0);
        }
    }

    // es epilogue (register-only + shfl; independent of LDS)
    float attv[8];
    #pragma unroll
    for (int ct = 0; ct < 8; ++ct) attv[ct] = att[n0 + ct * 16 + col];
    const int hbase = n0 >> 5;
    #pragma unroll
    for (int r = 0; r < 4; ++r) {
        float h0v = acc[0][r] * attv[0] + acc[1][r] * attv[1];
        float h1v = acc[2][r] * attv[2] + acc[3][r] * attv[3];
        float h2v = acc[4][r] * attv[4] + acc[5][r] * attv[5];
        float h3v = acc[6][r] * attv[6] + acc[7][r] * attv[7];
        #pragma unroll
        for (int off = 1; off < 16; off <<= 1) {
            h0v += __shfl_xor(h0v, off);
            h1v += __shfl_xor(h1v, off);
            h2v += __shfl_xor(h2v, off);
            h3v += __shfl_xor(h3v, off);
        }
        if (col == 0) {
            int gm = m0 + w * 16 + quad * 4 + r;
            if (gm < N_NODES)
                *(float4*)&e_out[gm * NH + hbase] = make_float4(h0v, h1v, h2v, h3v);
        }
    }

    // C writeback via LDS (reuse Bs; stride 144 ushorts -> conflict-free writes)
    __syncthreads();            // all Bs reads complete
    unsigned short* Cs = (unsigned short*)Bs;
    #pragma unroll
    for (int ct = 0; ct < 8; ++ct) {
        const int cc = ct * 16 + col;
        #pragma unroll
        for (int r = 0; r < 4; ++r)
            Cs[(w * 16 + quad * 4 + r) * 144 + cc] = f2bf(acc[ct][r]);
    }
    __syncthreads();
    {
        const int r = tid >> 2;
        const int c0 = (tid & 3) * 32;
        const int gm = m0 + r;
        if (gm < N_NODES) {
            #pragma unroll
            for (int q = 0; q < 4; ++q) {
                ushort8_t v = *(const ushort8_t*)&Cs[r * 144 + c0 + q * 8];
                *(ushort8_t*)&Cp[(size_t)gm * HC + n0 + c0 + q * 8] = v;
            }
        }
    }
}

// ---------------- pipelined edge-chunk helpers ----------------
__device__ inline void edge4(const float* __restrict__ es,
                             const unsigned short* __restrict__ hs,
                             int s_pre, int i, int cm,
                             int h_l, int lane, float ed_mine,
                             float& den, float4& acc) {
    const int i1 = (i + 1 < cm) ? i + 1 : cm;
    const int i2 = (i + 2 < cm) ? i + 2 : cm;
    const int i3 = (i + 3 < cm) ? i + 3 : cm;
    const int s0 = __shfl(s_pre, i);
    const int s1 = __shfl(s_pre, i1);
    const int s2 = __shfl(s_pre, i2);
    const int s3 = __shfl(s_pre, i3);
    float q0 = es[s0 * NH + h_l];
    float q1 = es[s1 * NH + h_l];
    float q2 = es[s2 * NH + h_l];
    float q3 = es[s3 * NH + h_l];
    const ushort4_t v0 = *(const ushort4_t*)&hs[(size_t)s0 * HC + lane * 4];
    const ushort4_t v1 = *(const ushort4_t*)&hs[(size_t)s1 * HC + lane * 4];
    const ushort4_t v2 = *(const ushort4_t*)&hs[(size_t)s2 * HC + lane * 4];
    const ushort4_t v3 = *(const ushort4_t*)&hs[(size_t)s3 * HC + lane * 4];
    q0 += ed_mine; q0 = (q0 >= 0.f) ? q0 : 0.2f * q0;
    q1 += ed_mine; q1 = (q1 >= 0.f) ? q1 : 0.2f * q1;
    q2 += ed_mine; q2 = (q2 >= 0.f) ? q2 : 0.2f * q2;
    q3 += ed_mine; q3 = (q3 >= 0.f) ? q3 : 0.2f * q3;
    const float x0 = __expf(q0);
    const float x1 = (i + 1 <= cm) ? __expf(q1) : 0.f;
    const float x2 = (i + 2 <= cm) ? __expf(q2) : 0.f;
    const float x3 = (i + 3 <= cm) ? __expf(q3) : 0.f;
    den += (x0 + x1) + (x2 + x3);
    acc.x += x0 * bf2f(v0[0]) + x1 * bf2f(v1[0]) + x2 * bf2f(v2[0]) + x3 * bf2f(v3[0]);
    acc.y += x0 * bf2f(v0[1]) + x1 * bf2f(v1[1]) + x2 * bf2f(v2[1]) + x3 * bf2f(v3[1]);
    acc.z += x0 * bf2f(v0[2]) + x1 * bf2f(v1[2]) + x2 * bf2f(v2[2]) + x3 * bf2f(v3[2]);
    acc.w += x0 * bf2f(v0[3]) + x1 * bf2f(v1[3]) + x2 * bf2f(v2[3]) + x3 * bf2f(v3[3]);
}

__device__ inline void edge1(const float* __restrict__ es,
                             const unsigned short* __restrict__ hs,
                             int s, int h_l, int lane, float ed_mine,
                             float& den, float4& acc) {
    float x = es[s * NH + h_l] + ed_mine;
    x = (x >= 0.f) ? x : 0.2f * x;
    const float ex = __expf(x);
    den += ex;
    const ushort4_t hv = *(const ushort4_t*)&hs[(size_t)s * HC + lane * 4];
    acc.x += ex * bf2f(hv[0]); acc.y += ex * bf2f(hv[1]);
    acc.z += ex * bf2f(hv[2]); acc.w += ex * bf2f(hv[3]);
}

// ---------------- FUSED layer1+layer2 per-node gather ----------------
// Fast path (cnt<=4) reads the dense edge table (independent 16B load in the
// prologue) -> one full memory round-trip removed from the dependent chain.
__global__ __launch_bounds__(256) void fused_gather_all(
        const int* __restrict__ row_ptr_g, const int* __restrict__ elist_g,
        const int* __restrict__ edense_g,
        const float* __restrict__ es_all, const float* __restrict__ ed1g,
        const unsigned short* __restrict__ hs_all,
        const float* __restrict__ b1, const float* __restrict__ b2,
        const float* __restrict__ gamma, const float* __restrict__ beta,
        const float* __restrict__ wd2,
        float* __restrict__ ed2g_all, float* __restrict__ deng_all,
        float* __restrict__ ppart) {
    const int t = blockIdx.y;
    const int* row_ptr = row_ptr_g + t * (N_NODES + 1);
    const int* elist = elist_g + t * N_EDGES;
    const int* eden = edense_g + (size_t)t * N_NODES * 4;
    const float* es1 = es_all + (size_t)t * N_NODES * NH;
    const float* es2 = es_all + (size_t)(6 + t) * N_NODES * NH;
    const unsigned short* hs1 = hs_all + (size_t)t * N_NODES * HC;
    const unsigned short* hs2 = hs_all + (size_t)(6 + t) * N_NODES * HC;
    const float* gam = gamma + t * HC;
    const float* bet = beta + t * HC;
    const float* w2 = wd2 + t * HC * NH;
    float* ed2g = ed2g_all + (size_t)t * N_NODES * NH;
    float* deng = deng_all + (size_t)t * N_NODES * NH;

    const int lane = threadIdx.x & 63;
    const int w = threadIdx.x >> 6;
    const int d = blockIdx.x * 4 + w;
    const int h_l = lane >> 3;

    // ---- prologue: three INDEPENDENT loads issued in parallel ----
    const float ed_mine = ed1g[((size_t)t * N_NODES + d) * NH + h_l];
    int dw = 0;
    if (lane < 4) dw = eden[d * 4 + lane];        // dense first-4 srcs
    const int e0 = row_ptr[d], e1n = row_ptr[d + 1];
    const int cnt = e1n - e0;
    const bool fast = (cnt > 0) && (cnt <= 4);

    int s_pre = 0;
    if (!fast) {                                   // CSR only for slow path
        if (lane < cnt) s_pre = elist[e0 + lane];
    }

    float den1 = 0.f, den2 = 0.f;
    float4 acc1 = make_float4(0.f, 0.f, 0.f, 0.f);
    float4 acc2 = make_float4(0.f, 0.f, 0.f, 0.f);

    float q20, q21, q22, q23;
    ushort4_t v20, v21, v22, v23;

    if (fast) {
        const int s0 = __shfl(dw, 0);
        const int s1 = __shfl(dw, 1);
        const int s2 = __shfl(dw, 2);
        const int s3 = __shfl(dw, 3);
        float q10 = es1[s0 * NH + h_l];
        float q11 = es1[s1 * NH + h_l];
        float q12 = es1[s2 * NH + h_l];
        float q13 = es1[s3 * NH + h_l];
        const ushort4_t v10 = *(const ushort4_t*)&hs1[(size_t)s0 * HC + lane * 4];
        const ushort4_t v11 = *(const ushort4_t*)&hs1[(size_t)s1 * HC + lane * 4];
        const ushort4_t v12 = *(const ushort4_t*)&hs1[(size_t)s2 * HC + lane * 4];
        const ushort4_t v13 = *(const ushort4_t*)&hs1[(size_t)s3 * HC + lane * 4];
        q20 = es2[s0 * NH + h_l];
        q21 = es2[s1 * NH + h_l];
        q22 = es2[s2 * NH + h_l];
        q23 = es2[s3 * NH + h_l];
        v20 = *(const ushort4_t*)&hs2[(size_t)s0 * HC + lane * 4];
        v21 = *(const ushort4_t*)&hs2[(size_t)s1 * HC + lane * 4];
        v22 = *(const ushort4_t*)&hs2[(size_t)s2 * HC + lane * 4];
        v23 = *(const ushort4_t*)&hs2[(size_t)s3 * HC + lane * 4];
        q10 += ed_mine; q10 = (q10 >= 0.f) ? q10 : 0.2f * q10;
        q11 += ed_mine; q11 = (q11 >= 0.f) ? q11 : 0.2f * q11;
        q12 += ed_mine; q12 = (q12 >= 0.f) ? q12 : 0.2f * q12;
        q13 += ed_mine; q13 = (q13 >= 0.f) ? q13 : 0.2f * q13;
        const float x0 = __expf(q10);
        const float x1 = (cnt > 1) ? __expf(q11) : 0.f;
        const float x2 = (cnt > 2) ? __expf(q12) : 0.f;
        const float x3 = (cnt > 3) ? __expf(q13) : 0.f;
        den1 = (x0 + x1) + (x2 + x3);
        acc1.x = x0 * bf2f(v10[0]) + x1 * bf2f(v11[0]) + x2 * bf2f(v12[0]) + x3 * bf2f(v13[0]);
        acc1.y = x0 * bf2f(v10[1]) + x1 * bf2f(v11[1]) + x2 * bf2f(v12[1]) + x3 * bf2f(v13[1]);
        acc1.z = x0 * bf2f(v10[2]) + x1 * bf2f(v11[2]) + x2 * bf2f(v12[2]) + x3 * bf2f(v13[2]);
        acc1.w = x0 * bf2f(v10[3]) + x1 * bf2f(v11[3]) + x2 * bf2f(v12[3]) + x3 * bf2f(v13[3]);
    } else if (cnt > 0) {
        const int c1 = (cnt < 64) ? cnt : 64;
        const int cm = c1 - 1;
        for (int i = 0; i < c1; i += 4)
            edge4(es1, hs1, s_pre, i, cm, h_l, lane, ed_mine, den1, acc1);
        if (cnt > 64)
            for (int ii = e0 + 64; ii < e1n; ++ii)
                edge1(es1, hs1, elist[ii], h_l, lane, ed_mine, den1, acc1);
    }

    const float inv1 = 1.f / (den1 + 1e-16f);
    const float4 bv1 = *(const float4*)&b1[t * HC + lane * 4];
    acc1.x = acc1.x * inv1 + bv1.x; acc1.y = acc1.y * inv1 + bv1.y;
    acc1.z = acc1.z * inv1 + bv1.z; acc1.w = acc1.w * inv1 + bv1.w;

    float s1 = acc1.x + acc1.y + acc1.z + acc1.w;
    float s2 = acc1.x * acc1.x + acc1.y * acc1.y + acc1.z * acc1.z + acc1.w * acc1.w;
    #pragma unroll
    for (int off = 1; off < 64; off <<= 1) { s1 += __shfl_xor(s1, off); s2 += __shfl_xor(s2, off); }
    const float mu = s1 * (1.f / 256.f);
    const float var = s2 * (1.f / 256.f) - mu * mu;
    const float rstd = rsqrtf(var + 1e-5f);
    const float4 g4 = *(const float4*)&gam[lane * 4];
    const float4 b4 = *(const float4*)&bet[lane * 4];
    const float ya0 = fmaxf((acc1.x - mu) * rstd * g4.x + b4.x, 0.f);
    const float ya1 = fmaxf((acc1.y - mu) * rstd * g4.y + b4.y, 0.f);
    const float ya2 = fmaxf((acc1.z - mu) * rstd * g4.z + b4.z, 0.f);
    const float ya3 = fmaxf((acc1.w - mu) * rstd * g4.w + b4.w, 0.f);

    __shared__ __align__(16) float ya_s[4][256];
    {
        const int c0 = lane * 4;
        const int widx = (c0 & ~31) | ((c0 & 31) ^ ((lane >> 3) << 2));
        *(float4*)&ya_s[w][widx] = make_float4(ya0, ya1, ya2, ya3);
    }
    const int k8 = lane >> 3;
    const int hh = lane & 7;
    const float* w2h = w2 + hh * HC;
    float e2 = 0.f;
    #pragma unroll
    for (int jj = 0; jj < 8; ++jj) {
        const int idx = k8 * 32 + ((jj * 4) ^ (k8 << 2));
        const float4 y = *(const float4*)&ya_s[w][idx];
        const float4 wv = *(const float4*)&w2h[k8 * 32 + jj * 4];
        e2 += y.x * wv.x + y.y * wv.y + y.z * wv.z + y.w * wv.w;
    }
    e2 += __shfl_xor(e2, 8);
    e2 += __shfl_xor(e2, 16);
    e2 += __shfl_xor(e2, 32);
    if (lane < 8) ed2g[d * NH + lane] = e2;
    const float ed2_mine = __shfl(e2, h_l);

    if (fast) {
        q20 += ed2_mine; q20 = (q20 >= 0.f) ? q20 : 0.2f * q20;
        q21 += ed2_mine; q21 = (q21 >= 0.f) ? q21 : 0.2f * q21;
        q22 += ed2_mine; q22 = (q22 >= 0.f) ? q22 : 0.2f * q22;
        q23 += ed2_mine; q23 = (q23 >= 0.f) ? q23 : 0.2f * q23;
        const float x0 = __expf(q20);
        const float x1 = (cnt > 1) ? __expf(q21) : 0.f;
        const float x2 = (cnt > 2) ? __expf(q22) : 0.f;
        const float x3 = (cnt > 3) ? __expf(q23) : 0.f;
        den2 = (x0 + x1) + (x2 + x3);
        acc2.x = x0 * bf2f(v20[0]) + x1 * bf2f(v21[0]) + x2 * bf2f(v22[0]) + x3 * bf2f(v23[0]);
        acc2.y = x0 * bf2f(v20[1]) + x1 * bf2f(v21[1]) + x2 * bf2f(v22[1]) + x3 * bf2f(v23[1]);
        acc2.z = x0 * bf2f(v20[2]) + x1 * bf2f(v21[2]) + x2 * bf2f(v22[2]) + x3 * bf2f(v23[2]);
        acc2.w = x0 * bf2f(v20[3]) + x1 * bf2f(v21[3]) + x2 * bf2f(v22[3]) + x3 * bf2f(v23[3]);
    } else if (cnt > 0) {
        const int c1 = (cnt < 64) ? cnt : 64;
        const int cm = c1 - 1;
        for (int i = 0; i < c1; i += 4)
            edge4(es2, hs2, s_pre, i, cm, h_l, lane, ed2_mine, den2, acc2);
        if (cnt > 64)
            for (int ii = e0 + 64; ii < e1n; ++ii)
                edge1(es2, hs2, elist[ii], h_l, lane, ed2_mine, den2, acc2);
    }

    if ((lane & 7) == 0) deng[d * NH + h_l] = den2;
    const float inv2 = 1.f / (den2 + 1e-16f);
    const float4 bv2 = *(const float4*)&b2[t * HC + lane * 4];
    acc2.x = acc2.x * inv2 + bv2.x; acc2.y = acc2.y * inv2 + bv2.y;
    acc2.z = acc2.z * inv2 + bv2.z; acc2.w = acc2.w * inv2 + bv2.w;

    float t1 = acc2.x + acc2.y + acc2.z + acc2.w;
    float t2 = acc2.x * acc2.x + acc2.y * acc2.y + acc2.z * acc2.z + acc2.w * acc2.w;
    #pragma unroll
    for (int off = 1; off < 64; off <<= 1) { t1 += __shfl_xor(t1, off); t2 += __shfl_xor(t2, off); }
    const float mu2 = t1 * (1.f / 256.f);
    const float var2 = t2 * (1.f / 256.f) - mu2 * mu2;
    const float rstd2 = rsqrtf(var2 + 1e-5f);
    float4 pool;
    pool.x = fmaxf((acc2.x - mu2) * rstd2 * g4.x + b4.x, 0.f);
    pool.y = fmaxf((acc2.y - mu2) * rstd2 * g4.y + b4.y, 0.f);
    pool.z = fmaxf((acc2.z - mu2) * rstd2 * g4.z + b4.z, 0.f);
    pool.w = fmaxf((acc2.w - mu2) * rstd2 * g4.w + b4.w, 0.f);

    // ---- block pool partial ----
    __shared__ __align__(16) float sacc[4][260];
    *(float4*)&sacc[w][lane * 4] = pool;
    __syncthreads();
    const int tid = threadIdx.x;
    float tot = sacc[0][tid] + sacc[1][tid] + sacc[2][tid] + sacc[3][tid];
    ppart[((size_t)t * FG_GRID + blockIdx.x) * HC + tid] = tot;
}

// ---------------- batched pooled-partial reduce ----------------
__global__ __launch_bounds__(256) void pool_reduce_all(const float* __restrict__ ppart,
                                                       float* __restrict__ psums) {
    int t = blockIdx.y;
    const float* part = ppart + (size_t)t * FG_GRID * HC;
    int tid = threadIdx.x;
    float acc = 0.f;
    for (int b = blockIdx.x; b < FG_GRID; b += gridDim.x)
        acc += part[(size_t)b * HC + tid];
    atomicAdd(&psums[t * HC + tid], acc);
}

// ---------------- batched alpha2 writer: one thread per EDGE (all 8 heads) ----
__global__ __launch_bounds__(256) void alpha_all(const int* __restrict__ ei,
                          const float* __restrict__ es_all,
                          const float* __restrict__ ed2g_all,
                          const float* __restrict__ deng_all,
                          float* __restrict__ out) {
    int t = blockIdx.y;
    int e = blockIdx.x * 256 + threadIdx.x;
    if (e >= N_EDGES) return;
    const int* src = ei + (size_t)t * 2 * N_EDGES;
    const int* dst = src + N_EDGES;
    const int s = src[e], d = dst[e];
    const float* esp = es_all + (size_t)(6 + t) * N_NODES * NH + (size_t)s * NH;
    const float* edp = ed2g_all + (size_t)t * N_NODES * NH + (size_t)d * NH;
    const float* dnp = deng_all + (size_t)t * N_NODES * NH + (size_t)d * NH;
    const float4 ea = *(const float4*)esp;
    const float4 eb = *(const float4*)(esp + 4);
    const float4 da = *(const float4*)edp;
    const float4 db = *(const float4*)(edp + 4);
    const float4 na = *(const float4*)dnp;
    const float4 nb = *(const float4*)(dnp + 4);
    float x[8];
    x[0] = ea.x + da.x; x[1] = ea.y + da.y; x[2] = ea.z + da.z; x[3] = ea.w + da.w;
    x[4] = eb.x + db.x; x[5] = eb.y + db.y; x[6] = eb.z + db.z; x[7] = eb.w + db.w;
    float n[8] = {na.x, na.y, na.z, na.w, nb.x, nb.y, nb.z, nb.w};
    float* op = out + (size_t)t * N_EDGES * NH + (size_t)e * NH;
    #pragma unroll
    for (int h = 0; h < 8; ++h) {
        float v = x[h];
        v = (v >= 0.f) ? v : 0.2f * v;
        op[h] = __expf(v) / (n[h] + 1e-16f);
    }
}

// ---------------- x_pkg column sums ----------------
__global__ __launch_bounds__(256) void pkg_accum(const float* __restrict__ x, float* __restrict__ sums) {
    int tid = threadIdx.x;
    int col = tid & 127;
    int rof = tid >> 7;
    float acc = 0.f;
    for (int r = blockIdx.x * 2 + rof; r < N_NODES; r += gridDim.x * 2)
        acc += x[(size_t)r * D_IN + col];
    atomicAdd(&sums[col], acc);
}

// ---------------- final classifier dot ----------------
__global__ __launch_bounds__(256) void logits_k(const float* __restrict__ psums,
                                                const float* __restrict__ ksums,
                                                const float* __restrict__ Wc,
                                                const float* __restrict__ bc,
                                                float* __restrict__ out) {
    int tid = threadIdx.x;
    const float inv = 1.f / (float)N_NODES;
    float acc = 0.f;
    for (int i = tid; i < N_TYPES * HC; i += 256) acc += psums[i] * inv * Wc[i];
    if (tid < D_IN) acc += ksums[tid] * inv * Wc[N_TYPES * HC + tid];
    #pragma unroll
    for (int off = 32; off; off >>= 1) acc += __shfl_down(acc, off);
    __shared__ float w[4];
    if ((tid & 63) == 0) w[tid >> 6] = acc;
    __syncthreads();
    if (tid == 0) out[0] = w[0] + w[1] + w[2] + w[3] + bc[0];
}

static inline void zf(float* p, int n, hipStream_t stream) {
    int n4 = (n + 3) >> 2;
    zero4<<<(n4 + 255) / 256, 256, 0, stream>>>((float4*)p, n4);
}

extern "C" void kernel_launch(void* const* d_in, const int* in_sizes, int n_in,
                              void* d_out, int out_size, void* d_ws, size_t ws_size,
                              hipStream_t stream) {
    const float* x_pkg    = (const float*)d_in[0];
    const float* x_tgt    = (const float*)d_in[1];
    const int*   ei       = (const int*)d_in[2];
    const float* W1_src   = (const float*)d_in[3];
    const float* W1_dst   = (const float*)d_in[4];
    const float* att1_src = (const float*)d_in[5];
    const float* att1_dst = (const float*)d_in[6];
    const float* b1       = (const float*)d_in[7];
    const float* W2_src   = (const float*)d_in[8];
    const float* W2_dst   = (const float*)d_in[9];
    const float* att2_src = (const float*)d_in[10];
    const float* att2_dst = (const float*)d_in[11];
    const float* b2       = (const float*)d_in[12];
    const float* gamma    = (const float*)d_in[13];
    const float* beta     = (const float*)d_in[14];
    const float* Wc       = (const float*)d_in[15];
    const float* bc       = (const float*)d_in[16];
    float* out = (float*)d_out;

    // ---- workspace layout ----
    char* wsb = (char*)d_ws;
    unsigned short* xpkg_bf = (unsigned short*)wsb;                    // 30000*128
    unsigned short* hs_all  = xpkg_bf + (size_t)N_NODES * D_IN;        // 12*30000*256
    float* es_all   = (float*)(hs_all + (size_t)12 * N_NODES * HC);    // 12*30000*8
    float* ed2g_all = es_all + (size_t)12 * N_NODES * NH;              // 6*30000*8
    float* deng_all = ed2g_all + (size_t)N_TYPES * N_NODES * NH;       // 6*30000*8
    float* psums    = deng_all + (size_t)N_TYPES * N_NODES * NH;       // 1536
    float* ksums    = psums + N_TYPES * HC;                            // 128
    float* wd1      = ksums + D_IN;                                    // 6*128*8 (transposed [h][k])
    float* wd2      = wd1 + N_TYPES * D_IN * NH;                       // 6*256*8 (transposed [h][c])
    unsigned short* Wt = (unsigned short*)(wd2 + N_TYPES * HC * NH);   // 12*256*128 bf16
    float* ed1g     = (float*)(Wt + (size_t)12 * HC * D_IN);           // 6*30000*8
    float* ppart    = ed1g + (size_t)N_TYPES * N_NODES * NH;           // 6*FG_GRID*256
    int* counts  = (int*)(ppart + (size_t)N_TYPES * FG_GRID * HC);     // 6*30000
    int* row_ptr = counts + N_TYPES * N_NODES;                         // 6*30001
    int* cursor  = row_ptr + N_TYPES * (N_NODES + 1);                  // 6*30000
    int* elist   = cursor + N_TYPES * N_NODES;                         // 6*100000
    int* edense  = elist + N_TYPES * N_EDGES;                          // 6*30000*4

    dim3 egrid((N_EDGES + 255) / 256, N_TYPES);

    // ---- setup ----
    zf(psums, N_TYPES * HC + D_IN, stream);   // psums + ksums contiguous
    pkg_accum<<<256, 256, 0, stream>>>(x_pkg, ksums);
    {
        int tot = N_TYPES * (D_IN + HC) * NH;
        att_weight_all<<<(tot + 255) / 256, 256, 0, stream>>>(W1_dst, att1_dst, W2_dst, att2_dst, wd1, wd2);
    }
    {
        dim3 g(4, 4, 12);
        wt_prep<<<g, 256, 0, stream>>>(W1_src, W2_src, Wt);
    }
    {
        dim3 g((N_NODES + 31) / 32, N_TYPES);
        ed1_all<<<g, 256, 0, stream>>>(x_tgt, wd1, ed1g);
    }
    to_bf16<<<((N_NODES * D_IN / 4) + 255) / 256, 256, 0, stream>>>(x_pkg, xpkg_bf, N_NODES * D_IN / 4);
    zero_i<<<(N_TYPES * N_NODES + 255) / 256, 256, 0, stream>>>(counts, N_TYPES * N_NODES);
    zero_i<<<(N_TYPES * N_NODES * 4 + 255) / 256, 256, 0, stream>>>(edense, N_TYPES * N_NODES * 4);
    hist_all<<<egrid, 256, 0, stream>>>(ei, counts);
    scan_all<<<N_TYPES, SCAN_T, 0, stream>>>(counts, row_ptr, cursor);
    fill_all<<<egrid, 256, 0, stream>>>(ei, row_ptr, cursor, elist, edense);

    // ---- one fat GEMM: all 12 src-side projections (n-tile 128) ----
    {
        dim3 g((N_NODES + 63) / 64, 2, 12);
        gemm_all<<<g, 256, 0, stream>>>(xpkg_bf, Wt, att1_src, att2_src,
                                        hs_all, es_all);
    }

    // ---- FUSED layer1 + layer2 ----
    {
        dim3 g(FG_GRID, N_TYPES);
        fused_gather_all<<<g, 256, 0, stream>>>(row_ptr, elist, edense, es_all, ed1g, hs_all,
                                                b1, b2, gamma, beta, wd2,
                                                ed2g_all, deng_all, ppart);
    }
    {
        dim3 g(64, N_TYPES);
        pool_reduce_all<<<g, 256, 0, stream>>>(ppart, psums);
    }
    {
        dim3 g((N_EDGES + 255) / 256, N_TYPES);
        alpha_all<<<g, 256, 0, stream>>>(ei, es_all, ed2g_all, deng_all, out + 1);
    }

    logits_k<<<1, 256, 0, stream>>>(psums, ksums, Wc, bc, out);
}

// Round 9
// 794.166 us; speedup vs baseline: 1.0990x; 1.0684x over previous
//
#include <hip/hip_runtime.h>
#include <hip/hip_bf16.h>
#include <cstddef>

#define N_NODES 30000
#define N_EDGES 100000
#define N_TYPES 6
#define D_IN 128
#define HC 256
#define NH 8
#define CH 32

typedef __attribute__((ext_vector_type(8))) unsigned short ushort8_t;
typedef __attribute__((ext_vector_type(4))) unsigned short ushort4_t;
typedef __attribute__((ext_vector_type(8))) __bf16 bf16x8;
typedef __attribute__((ext_vector_type(4))) float floatx4;

#define FG_GRID (N_NODES / 8)   // 3750 blocks per type, 2 nodes per wave

__device__ inline unsigned short f2bf(float f) {
    unsigned u = __float_as_uint(f);
    u += 0x7fffu + ((u >> 16) & 1u);
    return (unsigned short)(u >> 16);
}
__device__ inline float bf2f(unsigned short u) {
    return __uint_as_float(((unsigned)u) << 16);
}

// ---------------- fills / converts ----------------
__global__ void zero4(float4* __restrict__ p, int n4) {
    int g = blockIdx.x * blockDim.x + threadIdx.x;
    if (g < n4) p[g] = make_float4(0.f, 0.f, 0.f, 0.f);
}
__global__ void zero_i(int* __restrict__ p, int n) {
    int g = blockIdx.x * blockDim.x + threadIdx.x;
    if (g < n) p[g] = 0;
}
__global__ void to_bf16(const float* __restrict__ x, unsigned short* __restrict__ o, int n4) {
    int g = blockIdx.x * blockDim.x + threadIdx.x;
    if (g >= n4) return;
    float4 v = ((const float4*)x)[g];
    ushort4_t p;
    p[0] = f2bf(v.x); p[1] = f2bf(v.y); p[2] = f2bf(v.z); p[3] = f2bf(v.w);
    *(ushort4_t*)&o[(size_t)g * 4] = p;
}

// ---------------- batched CSR build (all 6 types) ----------------
__global__ void hist_all(const int* __restrict__ ei, int* __restrict__ counts) {
    int t = blockIdx.y;
    int e = blockIdx.x * 256 + threadIdx.x;
    if (e < N_EDGES)
        atomicAdd(&counts[t * N_NODES + ei[(size_t)t * 2 * N_EDGES + N_EDGES + e]], 1);
}

#define SCAN_T 1024
#define SCAN_C 30
__global__ __launch_bounds__(1024) void scan_all(const int* __restrict__ counts_g,
                                                 int* __restrict__ row_ptr_g,
                                                 int* __restrict__ cursor_g) {
    int t = blockIdx.x;
    const int* counts = counts_g + t * N_NODES;
    int* row_ptr = row_ptr_g + t * (N_NODES + 1);
    int* cursor = cursor_g + t * N_NODES;
    __shared__ int part[SCAN_T];
    int tid = threadIdx.x;
    int base = tid * SCAN_C;
    int loc[SCAN_C];
    int s = 0;
    #pragma unroll
    for (int i = 0; i < SCAN_C; ++i) {
        int idx = base + i;
        int v = (idx < N_NODES) ? counts[idx] : 0;
        loc[i] = s; s += v;
    }
    part[tid] = s;
    __syncthreads();
    int tot = s;
    for (int d = 1; d < SCAN_T; d <<= 1) {
        int v = (tid >= d) ? part[tid - d] : 0;
        __syncthreads();
        part[tid] += v;
        __syncthreads();
    }
    int off = part[tid] - tot;
    #pragma unroll
    for (int i = 0; i < SCAN_C; ++i) {
        int idx = base + i;
        if (idx < N_NODES) { int r = off + loc[i]; row_ptr[idx] = r; cursor[idx] = r; }
    }
    if (tid == SCAN_T - 1) row_ptr[N_NODES] = part[SCAN_T - 1];
}

// fill CSR + dense first-4-edges table (src only). edense pre-zeroed so
// unwritten slots read node 0 (harmless: their exp terms are masked by cnt).
__global__ void fill_all(const int* __restrict__ ei, const int* __restrict__ row_ptr_g,
                         int* __restrict__ cursor,
                         int* __restrict__ elist, int* __restrict__ edense) {
    int t = blockIdx.y;
    int e = blockIdx.x * 256 + threadIdx.x;
    if (e < N_EDGES) {
        const int* src = ei + (size_t)t * 2 * N_EDGES;
        const int* dst = src + N_EDGES;
        const int d = dst[e];
        int pos = atomicAdd(&cursor[t * N_NODES + d], 1);
        elist[t * N_EDGES + pos] = src[e];
        int loc = pos - row_ptr_g[t * (N_NODES + 1) + d];
        if (loc < 4)
            edense[((size_t)t * N_NODES + d) * 4 + loc] = src[e];
    }
}

// ---------------- attention dst-weight precompute (TRANSPOSED: [h][k]) ----------------
__global__ void att_weight_all(const float* __restrict__ W1d, const float* __restrict__ a1d,
                               const float* __restrict__ W2d, const float* __restrict__ a2d,
                               float* __restrict__ wd1, float* __restrict__ wd2) {
    int g = blockIdx.x * blockDim.x + threadIdx.x;
    const int per_t = (D_IN + HC) * NH;
    if (g >= N_TYPES * per_t) return;
    int t = g / per_t, r = g % per_t;
    if (r < D_IN * NH) {
        int k = r >> 3, h = r & 7;
        const float* wr = W1d + (size_t)t * D_IN * HC + (size_t)k * HC + h * CH;
        const float* ar = a1d + t * HC + h * CH;
        float s = 0.f;
        #pragma unroll
        for (int c = 0; c < CH; ++c) s += wr[c] * ar[c];
        wd1[t * D_IN * NH + h * D_IN + k] = s;          // transposed
    } else {
        r -= D_IN * NH;
        int k = r >> 3, h = r & 7;
        const float* wr = W2d + (size_t)t * HC * HC + (size_t)k * HC + h * CH;
        const float* ar = a2d + t * HC + h * CH;
        float s = 0.f;
        #pragma unroll
        for (int c = 0; c < CH; ++c) s += wr[c] * ar[c];
        wd2[t * HC * NH + h * HC + k] = s;              // transposed
    }
}

// ---------------- weight pre-transpose+convert: Wt[j][n][k] bf16 ----------------
__global__ __launch_bounds__(256) void wt_prep(const float* __restrict__ W1s,
                                               const float* __restrict__ W2s,
                                               unsigned short* __restrict__ Wt) {
    const int j = blockIdx.z;
    const float* W = (j < 6) ? W1s + (size_t)j * D_IN * HC
                             : W2s + (size_t)(j - 6) * D_IN * HC;
    const int n0 = blockIdx.x * 64;
    const int k0 = blockIdx.y * 32;
    __shared__ unsigned short tile[32][71];
    const int t = threadIdx.x;
    {
        const int k = t >> 3, n = (t & 7) * 8;
        const float4 a = *(const float4*)&W[(size_t)(k0 + k) * HC + n0 + n];
        const float4 b = *(const float4*)&W[(size_t)(k0 + k) * HC + n0 + n + 4];
        tile[k][n + 0] = f2bf(a.x); tile[k][n + 1] = f2bf(a.y);
        tile[k][n + 2] = f2bf(a.z); tile[k][n + 3] = f2bf(a.w);
        tile[k][n + 4] = f2bf(b.x); tile[k][n + 5] = f2bf(b.y);
        tile[k][n + 6] = f2bf(b.z); tile[k][n + 7] = f2bf(b.w);
    }
    __syncthreads();
    {
        const int n = t >> 2, k = (t & 3) * 8;
        ushort8_t v;
        #pragma unroll
        for (int q = 0; q < 8; ++q) v[q] = tile[k + q][n];
        *(ushort8_t*)&Wt[((size_t)j * HC + n0 + n) * D_IN + k0 + k] = v;
    }
}

// ---------------- layer-1 dst attention logits ----------------
__global__ __launch_bounds__(256) void ed1_all(const float* __restrict__ x_tgt,
                                               const float* __restrict__ wd1,
                                               float* __restrict__ ed1g) {
    const int t = blockIdx.y;
    const int lane = threadIdx.x & 63;
    const int wv = threadIdx.x >> 6;
    const int n8 = lane >> 3, h = lane & 7;
    const int node = blockIdx.x * 32 + wv * 8 + n8;
    if (node >= N_NODES) return;
    const float* xr = x_tgt + ((size_t)t * N_NODES + node) * D_IN;
    const float* wp = wd1 + t * D_IN * NH + h * D_IN;
    float acc = 0.f;
    #pragma unroll
    for (int k = 0; k < D_IN; k += 4) {
        const float4 x4 = *(const float4*)&xr[k];
        const float4 w4 = *(const float4*)&wp[k];
        acc += x4.x * w4.x + x4.y * w4.y + x4.z * w4.z + x4.w * w4.w;
    }
    ed1g[((size_t)t * N_NODES + node) * NH + h] = acc;
}

// ---------------- ONE batched MFMA GEMM over 12 jobs ----------------
__global__ __launch_bounds__(256) void gemm_all(const unsigned short* __restrict__ A,
                                                const unsigned short* __restrict__ Wt,
                                                const float* __restrict__ att1,
                                                const float* __restrict__ att2,
                                                unsigned short* __restrict__ hs_all,
                                                float* __restrict__ es_all) {
    const int j = blockIdx.z;
    const unsigned short* B = Wt + (size_t)j * HC * D_IN;   // [n][k] bf16
    const float* att = (j < 6) ? att1 + j * HC : att2 + (j - 6) * HC;
    unsigned short* Cp = hs_all + (size_t)j * N_NODES * HC;
    float* e_out = es_all + (size_t)j * N_NODES * NH;

    __shared__ __align__(16) unsigned short As[64 * 136];
    __shared__ __align__(16) unsigned short Bs[128 * 136];

    const int tid = threadIdx.x;
    const int w = tid >> 6;
    const int lane = tid & 63;
    const int col = lane & 15;
    const int quad = lane >> 4;
    const int m0 = blockIdx.x * 64;
    const int n0 = blockIdx.y * 128;

    // stage A 64x128 (4 x 16B per thread)
    {
        const int r = tid >> 2;
        const int kc = (tid & 3) * 8;
        const int gm = m0 + r;
        #pragma unroll
        for (int c = 0; c < 4; ++c) {
            ushort8_t v = (ushort8_t){0, 0, 0, 0, 0, 0, 0, 0};
            if (gm < N_NODES) v = *(const ushort8_t*)&A[(size_t)gm * D_IN + kc + c * 32];
            *(ushort8_t*)&As[r * 136 + kc + c * 32] = v;
        }
    }
    // stage B 128x128 (8 x 16B per thread)
    {
        const int r = tid >> 1;
        const int ks = (tid & 1) * 64;
        const unsigned short* br = &B[(size_t)(n0 + r) * D_IN + ks];
        #pragma unroll
        for (int q = 0; q < 8; ++q) {
            ushort8_t v = *(const ushort8_t*)&br[q * 8];
            *(ushort8_t*)&Bs[r * 136 + ks + q * 8] = v;
        }
    }
    __syncthreads();

    floatx4 acc[8];
    #pragma unroll
    for (int ct = 0; ct < 8; ++ct) acc[ct] = (floatx4){0.f, 0.f, 0.f, 0.f};

    #pragma unroll
    for (int ks = 0; ks < 4; ++ks) {
        ushort8_t araw = *(const ushort8_t*)&As[(w * 16 + col) * 136 + ks * 32 + quad * 8];
        bf16x8 af = __builtin_bit_cast(bf16x8, araw);
        #pragma unroll
        for (int ct = 0; ct < 8; ++ct) {
            ushort8_t braw = *(const ushort8_t*)&Bs[(ct * 16 + col) * 136 + ks * 32 + quad * 8];
            bf16x8 bf = __builtin_bit_cast(bf16x8, braw);
            acc[ct] = __builtin_amdgcn_mfma_f32_16x16x32_bf16(af, bf, acc[ct], 0, 0, 0);
        }
    }

    // es epilogue (register-only + shfl; independent of LDS)
    float attv[8];
    #pragma unroll
    for (int ct = 0; ct < 8; ++ct) attv[ct] = att[n0 + ct * 16 + col];
    const int hbase = n0 >> 5;
    #pragma unroll
    for (int r = 0; r < 4; ++r) {
        float h0v = acc[0][r] * attv[0] + acc[1][r] * attv[1];
        float h1v = acc[2][r] * attv[2] + acc[3][r] * attv[3];
        float h2v = acc[4][r] * attv[4] + acc[5][r] * attv[5];
        float h3v = acc[6][r] * attv[6] + acc[7][r] * attv[7];
        #pragma unroll
        for (int off = 1; off < 16; off <<= 1) {
            h0v += __shfl_xor(h0v, off);
            h1v += __shfl_xor(h1v, off);
            h2v += __shfl_xor(h2v, off);
            h3v += __shfl_xor(h3v, off);
        }
        if (col == 0) {
            int gm = m0 + w * 16 + quad * 4 + r;
            if (gm < N_NODES)
                *(float4*)&e_out[gm * NH + hbase] = make_float4(h0v, h1v, h2v, h3v);
        }
    }

    // C writeback via LDS (reuse Bs; stride 144 ushorts -> conflict-free writes)
    __syncthreads();            // all Bs reads complete
    unsigned short* Cs = (unsigned short*)Bs;
    #pragma unroll
    for (int ct = 0; ct < 8; ++ct) {
        const int cc = ct * 16 + col;
        #pragma unroll
        for (int r = 0; r < 4; ++r)
            Cs[(w * 16 + quad * 4 + r) * 144 + cc] = f2bf(acc[ct][r]);
    }
    __syncthreads();
    {
        const int r = tid >> 2;
        const int c0 = (tid & 3) * 32;
        const int gm = m0 + r;
        if (gm < N_NODES) {
            #pragma unroll
            for (int q = 0; q < 4; ++q) {
                ushort8_t v = *(const ushort8_t*)&Cs[r * 144 + c0 + q * 8];
                *(ushort8_t*)&Cp[(size_t)gm * HC + n0 + c0 + q * 8] = v;
            }
        }
    }
}

// ---------------- pipelined edge-chunk helpers ----------------
__device__ inline void edge4(const float* __restrict__ es,
                             const unsigned short* __restrict__ hs,
                             int s_pre, int i, int cm,
                             int h_l, int lane, float ed_mine,
                             float& den, float4& acc) {
    const int i1 = (i + 1 < cm) ? i + 1 : cm;
    const int i2 = (i + 2 < cm) ? i + 2 : cm;
    const int i3 = (i + 3 < cm) ? i + 3 : cm;
    const int s0 = __shfl(s_pre, i);
    const int s1 = __shfl(s_pre, i1);
    const int s2 = __shfl(s_pre, i2);
    const int s3 = __shfl(s_pre, i3);
    float q0 = es[s0 * NH + h_l];
    float q1 = es[s1 * NH + h_l];
    float q2 = es[s2 * NH + h_l];
    float q3 = es[s3 * NH + h_l];
    const ushort4_t v0 = *(const ushort4_t*)&hs[(size_t)s0 * HC + lane * 4];
    const ushort4_t v1 = *(const ushort4_t*)&hs[(size_t)s1 * HC + lane * 4];
    const ushort4_t v2 = *(const ushort4_t*)&hs[(size_t)s2 * HC + lane * 4];
    const ushort4_t v3 = *(const ushort4_t*)&hs[(size_t)s3 * HC + lane * 4];
    q0 += ed_mine; q0 = (q0 >= 0.f) ? q0 : 0.2f * q0;
    q1 += ed_mine; q1 = (q1 >= 0.f) ? q1 : 0.2f * q1;
    q2 += ed_mine; q2 = (q2 >= 0.f) ? q2 : 0.2f * q2;
    q3 += ed_mine; q3 = (q3 >= 0.f) ? q3 : 0.2f * q3;
    const float x0 = __expf(q0);
    const float x1 = (i + 1 <= cm) ? __expf(q1) : 0.f;
    const float x2 = (i + 2 <= cm) ? __expf(q2) : 0.f;
    const float x3 = (i + 3 <= cm) ? __expf(q3) : 0.f;
    den += (x0 + x1) + (x2 + x3);
    acc.x += x0 * bf2f(v0[0]) + x1 * bf2f(v1[0]) + x2 * bf2f(v2[0]) + x3 * bf2f(v3[0]);
    acc.y += x0 * bf2f(v0[1]) + x1 * bf2f(v1[1]) + x2 * bf2f(v2[1]) + x3 * bf2f(v3[1]);
    acc.z += x0 * bf2f(v0[2]) + x1 * bf2f(v1[2]) + x2 * bf2f(v2[2]) + x3 * bf2f(v3[2]);
    acc.w += x0 * bf2f(v0[3]) + x1 * bf2f(v1[3]) + x2 * bf2f(v2[3]) + x3 * bf2f(v3[3]);
}

__device__ inline void edge1(const float* __restrict__ es,
                             const unsigned short* __restrict__ hs,
                             int s, int h_l, int lane, float ed_mine,
                             float& den, float4& acc) {
    float x = es[s * NH + h_l] + ed_mine;
    x = (x >= 0.f) ? x : 0.2f * x;
    const float ex = __expf(x);
    den += ex;
    const ushort4_t hv = *(const ushort4_t*)&hs[(size_t)s * HC + lane * 4];
    acc.x += ex * bf2f(hv[0]); acc.y += ex * bf2f(hv[1]);
    acc.z += ex * bf2f(hv[2]); acc.w += ex * bf2f(hv[3]);
}

// ---------------- per-node fast-path buffer + math (verified R5 path) ----------------
struct FastBuf {
    float q10, q11, q12, q13, q20, q21, q22, q23;
    ushort4_t v10, v11, v12, v13, v20, v21, v22, v23;
};

__device__ inline FastBuf node_load_fast(int dw, int h_l, int lane,
        const float* __restrict__ es1, const float* __restrict__ es2,
        const unsigned short* __restrict__ hs1, const unsigned short* __restrict__ hs2) {
    FastBuf b;
    const int s0 = __shfl(dw, 0);
    const int s1 = __shfl(dw, 1);
    const int s2 = __shfl(dw, 2);
    const int s3 = __shfl(dw, 3);
    b.q10 = es1[s0 * NH + h_l];
    b.q11 = es1[s1 * NH + h_l];
    b.q12 = es1[s2 * NH + h_l];
    b.q13 = es1[s3 * NH + h_l];
    b.v10 = *(const ushort4_t*)&hs1[(size_t)s0 * HC + lane * 4];
    b.v11 = *(const ushort4_t*)&hs1[(size_t)s1 * HC + lane * 4];
    b.v12 = *(const ushort4_t*)&hs1[(size_t)s2 * HC + lane * 4];
    b.v13 = *(const ushort4_t*)&hs1[(size_t)s3 * HC + lane * 4];
    b.q20 = es2[s0 * NH + h_l];
    b.q21 = es2[s1 * NH + h_l];
    b.q22 = es2[s2 * NH + h_l];
    b.q23 = es2[s3 * NH + h_l];
    b.v20 = *(const ushort4_t*)&hs2[(size_t)s0 * HC + lane * 4];
    b.v21 = *(const ushort4_t*)&hs2[(size_t)s1 * HC + lane * 4];
    b.v22 = *(const ushort4_t*)&hs2[(size_t)s2 * HC + lane * 4];
    b.v23 = *(const ushort4_t*)&hs2[(size_t)s3 * HC + lane * 4];
    return b;
}

__device__ inline float4 node_math(
        bool fast, int cnt, int e0, int e1n, int s_pre, float ed_mine,
        const FastBuf& fb,
        const float* __restrict__ es1, const float* __restrict__ es2,
        const unsigned short* __restrict__ hs1, const unsigned short* __restrict__ hs2,
        const int* __restrict__ elist,
        const float4& bv1, const float4& bv2, const float4& g4, const float4& b4,
        float* ya_row, const float* __restrict__ w2h,
        int lane, int h_l, int d,
        float* __restrict__ ed2g, float* __restrict__ deng) {
    float den1 = 0.f, den2 = 0.f;
    float4 acc1 = make_float4(0.f, 0.f, 0.f, 0.f);
    float4 acc2 = make_float4(0.f, 0.f, 0.f, 0.f);

    if (fast) {
        float q10 = fb.q10 + ed_mine; q10 = (q10 >= 0.f) ? q10 : 0.2f * q10;
        float q11 = fb.q11 + ed_mine; q11 = (q11 >= 0.f) ? q11 : 0.2f * q11;
        float q12 = fb.q12 + ed_mine; q12 = (q12 >= 0.f) ? q12 : 0.2f * q12;
        float q13 = fb.q13 + ed_mine; q13 = (q13 >= 0.f) ? q13 : 0.2f * q13;
        const float x0 = __expf(q10);
        const float x1 = (cnt > 1) ? __expf(q11) : 0.f;
        const float x2 = (cnt > 2) ? __expf(q12) : 0.f;
        const float x3 = (cnt > 3) ? __expf(q13) : 0.f;
        den1 = (x0 + x1) + (x2 + x3);
        acc1.x = x0 * bf2f(fb.v10[0]) + x1 * bf2f(fb.v11[0]) + x2 * bf2f(fb.v12[0]) + x3 * bf2f(fb.v13[0]);
        acc1.y = x0 * bf2f(fb.v10[1]) + x1 * bf2f(fb.v11[1]) + x2 * bf2f(fb.v12[1]) + x3 * bf2f(fb.v13[1]);
        acc1.z = x0 * bf2f(fb.v10[2]) + x1 * bf2f(fb.v11[2]) + x2 * bf2f(fb.v12[2]) + x3 * bf2f(fb.v13[2]);
        acc1.w = x0 * bf2f(fb.v10[3]) + x1 * bf2f(fb.v11[3]) + x2 * bf2f(fb.v12[3]) + x3 * bf2f(fb.v13[3]);
    } else if (cnt > 0) {
        const int c1 = (cnt < 64) ? cnt : 64;
        const int cm = c1 - 1;
        for (int i = 0; i < c1; i += 4)
            edge4(es1, hs1, s_pre, i, cm, h_l, lane, ed_mine, den1, acc1);
        if (cnt > 64)
            for (int ii = e0 + 64; ii < e1n; ++ii)
                edge1(es1, hs1, elist[ii], h_l, lane, ed_mine, den1, acc1);
    }

    const float inv1 = 1.f / (den1 + 1e-16f);
    acc1.x = acc1.x * inv1 + bv1.x; acc1.y = acc1.y * inv1 + bv1.y;
    acc1.z = acc1.z * inv1 + bv1.z; acc1.w = acc1.w * inv1 + bv1.w;

    float s1 = acc1.x + acc1.y + acc1.z + acc1.w;
    float s2 = acc1.x * acc1.x + acc1.y * acc1.y + acc1.z * acc1.z + acc1.w * acc1.w;
    #pragma unroll
    for (int off = 1; off < 64; off <<= 1) { s1 += __shfl_xor(s1, off); s2 += __shfl_xor(s2, off); }
    const float mu = s1 * (1.f / 256.f);
    const float var = s2 * (1.f / 256.f) - mu * mu;
    const float rstd = rsqrtf(var + 1e-5f);
    const float ya0 = fmaxf((acc1.x - mu) * rstd * g4.x + b4.x, 0.f);
    const float ya1 = fmaxf((acc1.y - mu) * rstd * g4.y + b4.y, 0.f);
    const float ya2 = fmaxf((acc1.z - mu) * rstd * g4.z + b4.z, 0.f);
    const float ya3 = fmaxf((acc1.w - mu) * rstd * g4.w + b4.w, 0.f);

    // ed2 = ya . wd2[:,h] via XOR-swizzled LDS transpose (wave-private row)
    {
        const int c0 = lane * 4;
        const int widx = (c0 & ~31) | ((c0 & 31) ^ ((lane >> 3) << 2));
        *(float4*)&ya_row[widx] = make_float4(ya0, ya1, ya2, ya3);
    }
    const int k8 = lane >> 3;
    float e2 = 0.f;
    #pragma unroll
    for (int jj = 0; jj < 8; ++jj) {
        const int idx = k8 * 32 + ((jj * 4) ^ (k8 << 2));
        const float4 y = *(const float4*)&ya_row[idx];
        const float4 wv = *(const float4*)&w2h[k8 * 32 + jj * 4];
        e2 += y.x * wv.x + y.y * wv.y + y.z * wv.z + y.w * wv.w;
    }
    e2 += __shfl_xor(e2, 8);
    e2 += __shfl_xor(e2, 16);
    e2 += __shfl_xor(e2, 32);
    if (lane < 8) ed2g[d * NH + lane] = e2;
    const float ed2_mine = __shfl(e2, h_l);

    if (fast) {
        float q20 = fb.q20 + ed2_mine; q20 = (q20 >= 0.f) ? q20 : 0.2f * q20;
        float q21 = fb.q21 + ed2_mine; q21 = (q21 >= 0.f) ? q21 : 0.2f * q21;
        float q22 = fb.q22 + ed2_mine; q22 = (q22 >= 0.f) ? q22 : 0.2f * q22;
        float q23 = fb.q23 + ed2_mine; q23 = (q23 >= 0.f) ? q23 : 0.2f * q23;
        const float x0 = __expf(q20);
        const float x1 = (cnt > 1) ? __expf(q21) : 0.f;
        const float x2 = (cnt > 2) ? __expf(q22) : 0.f;
        const float x3 = (cnt > 3) ? __expf(q23) : 0.f;
        den2 = (x0 + x1) + (x2 + x3);
        acc2.x = x0 * bf2f(fb.v20[0]) + x1 * bf2f(fb.v21[0]) + x2 * bf2f(fb.v22[0]) + x3 * bf2f(fb.v23[0]);
        acc2.y = x0 * bf2f(fb.v20[1]) + x1 * bf2f(fb.v21[1]) + x2 * bf2f(fb.v22[1]) + x3 * bf2f(fb.v23[1]);
        acc2.z = x0 * bf2f(fb.v20[2]) + x1 * bf2f(fb.v21[2]) + x2 * bf2f(fb.v22[2]) + x3 * bf2f(fb.v23[2]);
        acc2.w = x0 * bf2f(fb.v20[3]) + x1 * bf2f(fb.v21[3]) + x2 * bf2f(fb.v22[3]) + x3 * bf2f(fb.v23[3]);
    } else if (cnt > 0) {
        const int c1 = (cnt < 64) ? cnt : 64;
        const int cm = c1 - 1;
        for (int i = 0; i < c1; i += 4)
            edge4(es2, hs2, s_pre, i, cm, h_l, lane, ed2_mine, den2, acc2);
        if (cnt > 64)
            for (int ii = e0 + 64; ii < e1n; ++ii)
                edge1(es2, hs2, elist[ii], h_l, lane, ed2_mine, den2, acc2);
    }

    if ((lane & 7) == 0) deng[d * NH + h_l] = den2;
    const float inv2 = 1.f / (den2 + 1e-16f);
    acc2.x = acc2.x * inv2 + bv2.x; acc2.y = acc2.y * inv2 + bv2.y;
    acc2.z = acc2.z * inv2 + bv2.z; acc2.w = acc2.w * inv2 + bv2.w;

    float t1 = acc2.x + acc2.y + acc2.z + acc2.w;
    float t2 = acc2.x * acc2.x + acc2.y * acc2.y + acc2.z * acc2.z + acc2.w * acc2.w;
    #pragma unroll
    for (int off = 1; off < 64; off <<= 1) { t1 += __shfl_xor(t1, off); t2 += __shfl_xor(t2, off); }
    const float mu2 = t1 * (1.f / 256.f);
    const float var2 = t2 * (1.f / 256.f) - mu2 * mu2;
    const float rstd2 = rsqrtf(var2 + 1e-5f);
    float4 pool;
    pool.x = fmaxf((acc2.x - mu2) * rstd2 * g4.x + b4.x, 0.f);
    pool.y = fmaxf((acc2.y - mu2) * rstd2 * g4.y + b4.y, 0.f);
    pool.z = fmaxf((acc2.z - mu2) * rstd2 * g4.z + b4.z, 0.f);
    pool.w = fmaxf((acc2.w - mu2) * rstd2 * g4.w + b4.w, 0.f);
    return pool;
}

// ---------------- FUSED layer1+layer2: TWO nodes per wave (2x MLP) ----------------
__global__ __launch_bounds__(256) void fused_gather_all(
        const int* __restrict__ row_ptr_g, const int* __restrict__ elist_g,
        const int* __restrict__ edense_g,
        const float* __restrict__ es_all, const float* __restrict__ ed1g,
        const unsigned short* __restrict__ hs_all,
        const float* __restrict__ b1, const float* __restrict__ b2,
        const float* __restrict__ gamma, const float* __restrict__ beta,
        const float* __restrict__ wd2,
        float* __restrict__ ed2g_all, float* __restrict__ deng_all,
        float* __restrict__ ppart) {
    const int t = blockIdx.y;
    const int* row_ptr = row_ptr_g + t * (N_NODES + 1);
    const int* elist = elist_g + t * N_EDGES;
    const int* eden = edense_g + (size_t)t * N_NODES * 4;
    const float* es1 = es_all + (size_t)t * N_NODES * NH;
    const float* es2 = es_all + (size_t)(6 + t) * N_NODES * NH;
    const unsigned short* hs1 = hs_all + (size_t)t * N_NODES * HC;
    const unsigned short* hs2 = hs_all + (size_t)(6 + t) * N_NODES * HC;
    float* ed2g = ed2g_all + (size_t)t * N_NODES * NH;
    float* deng = deng_all + (size_t)t * N_NODES * NH;

    const int lane = threadIdx.x & 63;
    const int w = threadIdx.x >> 6;
    const int dA = blockIdx.x * 8 + w * 2;
    const int dB = dA + 1;
    const int h_l = lane >> 3;

    // ---- prologue: independent loads for BOTH nodes issued together ----
    const float edmA = ed1g[((size_t)t * N_NODES + dA) * NH + h_l];
    const float edmB = ed1g[((size_t)t * N_NODES + dB) * NH + h_l];
    int dwA = 0, dwB = 0;
    if (lane < 4) {
        dwA = eden[dA * 4 + lane];
        dwB = eden[dB * 4 + lane];
    }
    const int e0A = row_ptr[dA];
    const int e1nA = row_ptr[dA + 1];
    const int e1nB = row_ptr[dA + 2];
    const int e0B = e1nA;
    const int cntA = e1nA - e0A, cntB = e1nB - e0B;
    const bool fastA = (cntA > 0) && (cntA <= 4);
    const bool fastB = (cntB > 0) && (cntB <= 4);

    int s_preA = 0, s_preB = 0;
    if (!fastA) { if (lane < cntA) s_preA = elist[e0A + lane]; }
    if (!fastB) { if (lane < cntB) s_preB = elist[e0B + lane]; }

    // issue BOTH nodes' fast gather sets before any compute (wave-uniform branches)
    FastBuf fbA, fbB;
    if (fastA) fbA = node_load_fast(dwA, h_l, lane, es1, es2, hs1, hs2);
    if (fastB) fbB = node_load_fast(dwB, h_l, lane, es1, es2, hs1, hs2);

    const float4 bv1 = *(const float4*)&b1[t * HC + lane * 4];
    const float4 bv2 = *(const float4*)&b2[t * HC + lane * 4];
    const float4 g4 = *(const float4*)&gamma[t * HC + lane * 4];
    const float4 b4 = *(const float4*)&beta[t * HC + lane * 4];
    const float* w2h = wd2 + t * HC * NH + (lane & 7) * HC;

    __shared__ __align__(16) float ya_s[4][256];

    const float4 poolA = node_math(fastA, cntA, e0A, e1nA, s_preA, edmA, fbA,
                                   es1, es2, hs1, hs2, elist, bv1, bv2, g4, b4,
                                   &ya_s[w][0], w2h, lane, h_l, dA, ed2g, deng);
    const float4 poolB = node_math(fastB, cntB, e0B, e1nB, s_preB, edmB, fbB,
                                   es1, es2, hs1, hs2, elist, bv1, bv2, g4, b4,
                                   &ya_s[w][0], w2h, lane, h_l, dB, ed2g, deng);

    float4 pool;
    pool.x = poolA.x + poolB.x;
    pool.y = poolA.y + poolB.y;
    pool.z = poolA.z + poolB.z;
    pool.w = poolA.w + poolB.w;

    // ---- block pool partial (8 nodes per block) ----
    __shared__ __align__(16) float sacc[4][260];
    *(float4*)&sacc[w][lane * 4] = pool;
    __syncthreads();
    const int tid = threadIdx.x;
    float tot = sacc[0][tid] + sacc[1][tid] + sacc[2][tid] + sacc[3][tid];
    ppart[((size_t)t * FG_GRID + blockIdx.x) * HC + tid] = tot;
}

// ---------------- batched pooled-partial reduce ----------------
__global__ __launch_bounds__(256) void pool_reduce_all(const float* __restrict__ ppart,
                                                       float* __restrict__ psums) {
    int t = blockIdx.y;
    const float* part = ppart + (size_t)t * FG_GRID * HC;
    int tid = threadIdx.x;
    float acc = 0.f;
    for (int b = blockIdx.x; b < FG_GRID; b += gridDim.x)
        acc += part[(size_t)b * HC + tid];
    atomicAdd(&psums[t * HC + tid], acc);
}

// ---------------- batched alpha2 writer: one thread per EDGE (all 8 heads) ----
__global__ __launch_bounds__(256) void alpha_all(const int* __restrict__ ei,
                          const float* __restrict__ es_all,
                          const float* __restrict__ ed2g_all,
                          const float* __restrict__ deng_all,
                          float* __restrict__ out) {
    int t = blockIdx.y;
    int e = blockIdx.x * 256 + threadIdx.x;
    if (e >= N_EDGES) return;
    const int* src = ei + (size_t)t * 2 * N_EDGES;
    const int* dst = src + N_EDGES;
    const int s = src[e], d = dst[e];
    const float* esp = es_all + (size_t)(6 + t) * N_NODES * NH + (size_t)s * NH;
    const float* edp = ed2g_all + (size_t)t * N_NODES * NH + (size_t)d * NH;
    const float* dnp = deng_all + (size_t)t * N_NODES * NH + (size_t)d * NH;
    const float4 ea = *(const float4*)esp;
    const float4 eb = *(const float4*)(esp + 4);
    const float4 da = *(const float4*)edp;
    const float4 db = *(const float4*)(edp + 4);
    const float4 na = *(const float4*)dnp;
    const float4 nb = *(const float4*)(dnp + 4);
    float x[8];
    x[0] = ea.x + da.x; x[1] = ea.y + da.y; x[2] = ea.z + da.z; x[3] = ea.w + da.w;
    x[4] = eb.x + db.x; x[5] = eb.y + db.y; x[6] = eb.z + db.z; x[7] = eb.w + db.w;
    float n[8] = {na.x, na.y, na.z, na.w, nb.x, nb.y, nb.z, nb.w};
    float* op = out + (size_t)t * N_EDGES * NH + (size_t)e * NH;
    #pragma unroll
    for (int h = 0; h < 8; ++h) {
        float v = x[h];
        v = (v >= 0.f) ? v : 0.2f * v;
        op[h] = __expf(v) / (n[h] + 1e-16f);
    }
}

// ---------------- x_pkg column sums ----------------
__global__ __launch_bounds__(256) void pkg_accum(const float* __restrict__ x, float* __restrict__ sums) {
    int tid = threadIdx.x;
    int col = tid & 127;
    int rof = tid >> 7;
    float acc = 0.f;
    for (int r = blockIdx.x * 2 + rof; r < N_NODES; r += gridDim.x * 2)
        acc += x[(size_t)r * D_IN + col];
    atomicAdd(&sums[col], acc);
}

// ---------------- final classifier dot ----------------
__global__ __launch_bounds__(256) void logits_k(const float* __restrict__ psums,
                                                const float* __restrict__ ksums,
                                                const float* __restrict__ Wc,
                                                const float* __restrict__ bc,
                                                float* __restrict__ out) {
    int tid = threadIdx.x;
    const float inv = 1.f / (float)N_NODES;
    float acc = 0.f;
    for (int i = tid; i < N_TYPES * HC; i += 256) acc += psums[i] * inv * Wc[i];
    if (tid < D_IN) acc += ksums[tid] * inv * Wc[N_TYPES * HC + tid];
    #pragma unroll
    for (int off = 32; off; off >>= 1) acc += __shfl_down(acc, off);
    __shared__ float w[4];
    if ((tid & 63) == 0) w[tid >> 6] = acc;
    __syncthreads();
    if (tid == 0) out[0] = w[0] + w[1] + w[2] + w[3] + bc[0];
}

static inline void zf(float* p, int n, hipStream_t stream) {
    int n4 = (n + 3) >> 2;
    zero4<<<(n4 + 255) / 256, 256, 0, stream>>>((float4*)p, n4);
}

extern "C" void kernel_launch(void* const* d_in, const int* in_sizes, int n_in,
                              void* d_out, int out_size, void* d_ws, size_t ws_size,
                              hipStream_t stream) {
    const float* x_pkg    = (const float*)d_in[0];
    const float* x_tgt    = (const float*)d_in[1];
    const int*   ei       = (const int*)d_in[2];
    const float* W1_src   = (const float*)d_in[3];
    const float* W1_dst   = (const float*)d_in[4];
    const float* att1_src = (const float*)d_in[5];
    const float* att1_dst = (const float*)d_in[6];
    const float* b1       = (const float*)d_in[7];
    const float* W2_src   = (const float*)d_in[8];
    const float* W2_dst   = (const float*)d_in[9];
    const float* att2_src = (const float*)d_in[10];
    const float* att2_dst = (const float*)d_in[11];
    const float* b2       = (const float*)d_in[12];
    const float* gamma    = (const float*)d_in[13];
    const float* beta     = (const float*)d_in[14];
    const float* Wc       = (const float*)d_in[15];
    const float* bc       = (const float*)d_in[16];
    float* out = (float*)d_out;

    // ---- workspace layout ----
    char* wsb = (char*)d_ws;
    unsigned short* xpkg_bf = (unsigned short*)wsb;                    // 30000*128
    unsigned short* hs_all  = xpkg_bf + (size_t)N_NODES * D_IN;        // 12*30000*256
    float* es_all   = (float*)(hs_all + (size_t)12 * N_NODES * HC);    // 12*30000*8
    float* ed2g_all = es_all + (size_t)12 * N_NODES * NH;              // 6*30000*8
    float* deng_all = ed2g_all + (size_t)N_TYPES * N_NODES * NH;       // 6*30000*8
    float* psums    = deng_all + (size_t)N_TYPES * N_NODES * NH;       // 1536
    float* ksums    = psums + N_TYPES * HC;                            // 128
    float* wd1      = ksums + D_IN;                                    // 6*128*8 (transposed [h][k])
    float* wd2      = wd1 + N_TYPES * D_IN * NH;                       // 6*256*8 (transposed [h][c])
    unsigned short* Wt = (unsigned short*)(wd2 + N_TYPES * HC * NH);   // 12*256*128 bf16
    float* ed1g     = (float*)(Wt + (size_t)12 * HC * D_IN);           // 6*30000*8
    float* ppart    = ed1g + (size_t)N_TYPES * N_NODES * NH;           // 6*FG_GRID*256
    int* counts  = (int*)(ppart + (size_t)N_TYPES * FG_GRID * HC);     // 6*30000
    int* row_ptr = counts + N_TYPES * N_NODES;                         // 6*30001
    int* cursor  = row_ptr + N_TYPES * (N_NODES + 1);                  // 6*30000
    int* elist   = cursor + N_TYPES * N_NODES;                         // 6*100000
    int* edense  = elist + N_TYPES * N_EDGES;                          // 6*30000*4

    dim3 egrid((N_EDGES + 255) / 256, N_TYPES);

    // ---- setup ----
    zf(psums, N_TYPES * HC + D_IN, stream);   // psums + ksums contiguous
    pkg_accum<<<256, 256, 0, stream>>>(x_pkg, ksums);
    {
        int tot = N_TYPES * (D_IN + HC) * NH;
        att_weight_all<<<(tot + 255) / 256, 256, 0, stream>>>(W1_dst, att1_dst, W2_dst, att2_dst, wd1, wd2);
    }
    {
        dim3 g(4, 4, 12);
        wt_prep<<<g, 256, 0, stream>>>(W1_src, W2_src, Wt);
    }
    {
        dim3 g((N_NODES + 31) / 32, N_TYPES);
        ed1_all<<<g, 256, 0, stream>>>(x_tgt, wd1, ed1g);
    }
    to_bf16<<<((N_NODES * D_IN / 4) + 255) / 256, 256, 0, stream>>>(x_pkg, xpkg_bf, N_NODES * D_IN / 4);
    zero_i<<<(N_TYPES * N_NODES + 255) / 256, 256, 0, stream>>>(counts, N_TYPES * N_NODES);
    zero_i<<<(N_TYPES * N_NODES * 4 + 255) / 256, 256, 0, stream>>>(edense, N_TYPES * N_NODES * 4);
    hist_all<<<egrid, 256, 0, stream>>>(ei, counts);
    scan_all<<<N_TYPES, SCAN_T, 0, stream>>>(counts, row_ptr, cursor);
    fill_all<<<egrid, 256, 0, stream>>>(ei, row_ptr, cursor, elist, edense);

    // ---- one fat GEMM: all 12 src-side projections (n-tile 128) ----
    {
        dim3 g((N_NODES + 63) / 64, 2, 12);
        gemm_all<<<g, 256, 0, stream>>>(xpkg_bf, Wt, att1_src, att2_src,
                                        hs_all, es_all);
    }

    // ---- FUSED layer1 + layer2 (2 nodes per wave) ----
    {
        dim3 g(FG_GRID, N_TYPES);
        fused_gather_all<<<g, 256, 0, stream>>>(row_ptr, elist, edense, es_all, ed1g, hs_all,
                                                b1, b2, gamma, beta, wd2,
                                                ed2g_all, deng_all, ppart);
    }
    {
        dim3 g(64, N_TYPES);
        pool_reduce_all<<<g, 256, 0, stream>>>(ppart, psums);
    }
    {
        dim3 g((N_EDGES + 255) / 256, N_TYPES);
        alpha_all<<<g, 256, 0, stream>>>(ei, es_all, ed2g_all, deng_all, out + 1);
    }

    logits_k<<<1, 256, 0, stream>>>(psums, ksums, Wc, bc, out);
}